// Round 11
// baseline (178.591 us; speedup 1.0000x reference)
//
#include <hip/hip_runtime.h>
#include <hip/hip_bf16.h>
#include <math.h>

// Problem constants (match reference)
#define BB   1024
#define MM   16
#define KK   32
#define LL   50
#define EE   64
#define NACT 100000

typedef __attribute__((ext_vector_type(8))) short short8;
typedef float v4f __attribute__((ext_vector_type(4)));

__device__ __forceinline__ float rcpf(float x) { return __builtin_amdgcn_rcpf(x); }
// native 2^x (v_exp_f32 IS exp2)
__device__ __forceinline__ float exp2_fast(float x) {
    float r;
    asm("v_exp_f32 %0, %1" : "=v"(r) : "v"(x));
    return r;
}

// packed f32x2 -> bf16x2 (lo->low16, hi->high16), RNE
__device__ __forceinline__ unsigned cvt_pk_bf16(float lo, float hi) {
    unsigned r;
    asm("v_cvt_pk_bf16_f32 %0, %1, %2" : "=v"(r) : "v"(lo), "v"(hi));
    return r;
}
// two float4 (8 consecutive f32) -> one bf16x8 A-frag half
__device__ __forceinline__ short8 pack_frag(const float4& a, const float4& b) {
    uint4 o;
    o.x = cvt_pk_bf16(a.x, a.y);
    o.y = cvt_pk_bf16(a.z, a.w);
    o.z = cvt_pk_bf16(b.x, b.y);
    o.w = cvt_pk_bf16(b.z, b.w);
    return __builtin_bit_cast(short8, o);
}

// Block-wide barrier that does NOT drain vmcnt: LDS writes are made visible
// (lgkmcnt(0)) but global prefetch loads stay in flight across the barrier.
__device__ __forceinline__ void block_sync_lds() {
    __builtin_amdgcn_sched_barrier(0);
    asm volatile("s_waitcnt lgkmcnt(0)" ::: "memory");
    __builtin_amdgcn_s_barrier();
    __builtin_amdgcn_sched_barrier(0);
}

// ---------------------------------------------------------------------------
// MFMA LSTM, dual-chain + exp2 fold (r10 structure) + fused f32 x-gather:
// 512 blocks x 256 threads; 32 seqs/block as two independent 16-seq chains
// per wave. x A-frags are gathered straight from the f32 act_table (two
// float4 per frag half) and converted in-register with RNE cvt_pk --
// bit-identical to the former cvt_table pre-pass, which is now deleted.
// Weight columns & biases pre-scaled by -log2e (i,f,o) / +2*log2e (g) so
// MFMA output feeds v_exp_f32 (=2^x) directly. Weights in registers
// (64 VGPR); h via swizzled bf16 LDS double buffer; prefetch f32 loads
// issued top-of-step, left in flight across the non-draining barrier.
// ---------------------------------------------------------------------------
__global__ __launch_bounds__(256, 2)
void lstm_mfma(const int* __restrict__ act_seqs, const float* __restrict__ act_table,
               const float* __restrict__ W_ih, const float* __restrict__ W_hh,
               const float* __restrict__ b_ih, const float* __restrict__ b_hh,
               float* __restrict__ m_act)
{
    __shared__ __align__(16) short sH[4][1024];   // tile = buf*2 + chain; [16][64] bf16 swizzled
    __shared__ int sIdx[32 * LL];

    const int t    = threadIdx.x;
    const int blk  = blockIdx.x;
    const int lane = t & 63;
    const int w    = t >> 6;        // wave id = e-block (0..3)
    const int lr   = lane & 15;     // A row (seq) / B,D col selector
    const int lb   = lane >> 4;     // k-block / D row-block selector

    // --- this block's indices (contiguous 1600 ints, coalesced)
    for (int i = t; i < 32 * LL; i += 256) sIdx[i] = act_seqs[blk * (32 * LL) + i];

    // per-gate exp2 fold scales (i,f,o: -log2e; g: +2*log2e)
    const float L2E = 1.44269504088896f;
    float gscale[4];
    gscale[0] = -L2E; gscale[1] = -L2E; gscale[2] = 2.0f * L2E; gscale[3] = -L2E;

    // --- weights -> register B-frags, SCALED. gates = in @ W^T => B[k][j]=W[j][k].
    // lane holds col j = g*64 + 16w + lr, k = 32*ks + 8*lb + i.
    short8 Bf[2][4][2];   // [mat(ih,hh)][gate][ks]
    #pragma unroll
    for (int mat = 0; mat < 2; ++mat) {
        const float* W = mat ? W_hh : W_ih;
        #pragma unroll
        for (int g = 0; g < 4; ++g) {
            const int j = g * 64 + w * 16 + lr;
            const float sc = gscale[g];
            #pragma unroll
            for (int ks = 0; ks < 2; ++ks) {
                const float4* p = reinterpret_cast<const float4*>(&W[(size_t)j * 64 + ks * 32 + lb * 8]);
                float4 v0 = p[0], v1 = p[1];
                uint4 o;
                o.x = cvt_pk_bf16(sc * v0.x, sc * v0.y);
                o.y = cvt_pk_bf16(sc * v0.z, sc * v0.w);
                o.z = cvt_pk_bf16(sc * v1.x, sc * v1.y);
                o.w = cvt_pk_bf16(sc * v1.z, sc * v1.w);
                Bf[mat][g][ks] = __builtin_bit_cast(short8, o);
            }
        }
    }
    float bias[4];
    #pragma unroll
    for (int g = 0; g < 4; ++g) {
        const int j = g * 64 + w * 16 + lr;
        bias[g] = gscale[g] * (b_ih[j] + b_hh[j]);
    }

    float hA[4], cA[4], hB[4], cB[4];
    #pragma unroll
    for (int r = 0; r < 4; ++r) { hA[r] = 0.0f; cA[r] = 0.0f; hB[r] = 0.0f; cB[r] = 0.0f; }

    // zero buf0 (tiles 0,1 = 4096 B = 256 x uint4)
    reinterpret_cast<uint4*>(sH)[t] = make_uint4(0u, 0u, 0u, 0u);
    __syncthreads();   // sIdx + sH buf0 visible (once, outside loop)

    // --- x gather (f32): lane's frag halves = bytes [id*256 + lb*32 .. +31]
    // (ks=0: elements 8lb..8lb+7) and [id*256 + 128 + lb*32 ..] (ks=1).
    const char* tblf = reinterpret_cast<const char*>(act_table) + lb * 32;
    const int ibA = lr * LL;           // chain A: seq lr
    const int ibB = (16 + lr) * LL;    // chain B: seq 16+lr

    int idA = sIdx[ibA + 0], idB = sIdx[ibB + 0];
    float4 pA0 = *reinterpret_cast<const float4*>(tblf + (size_t)idA * 256);
    float4 pA1 = *reinterpret_cast<const float4*>(tblf + (size_t)idA * 256 + 16);
    float4 pA2 = *reinterpret_cast<const float4*>(tblf + (size_t)idA * 256 + 128);
    float4 pA3 = *reinterpret_cast<const float4*>(tblf + (size_t)idA * 256 + 144);
    float4 pB0 = *reinterpret_cast<const float4*>(tblf + (size_t)idB * 256);
    float4 pB1 = *reinterpret_cast<const float4*>(tblf + (size_t)idB * 256 + 16);
    float4 pB2 = *reinterpret_cast<const float4*>(tblf + (size_t)idB * 256 + 128);
    float4 pB3 = *reinterpret_cast<const float4*>(tblf + (size_t)idB * 256 + 144);
    idA = sIdx[ibA + 1]; idB = sIdx[ibB + 1];

    // LDS byte offsets (loop-invariant)
    const int offA0 = lr * 128 + ((lb ^ (lr & 7)) << 4);
    const int offA1 = lr * 128 + (((lb + 4) ^ (lr & 7)) << 4);
    int hw_off[4];
    #pragma unroll
    for (int r = 0; r < 4; ++r) {
        const int s = lb * 4 + r, e = w * 16 + lr;
        hw_off[r] = s * 128 + ((((e >> 3) ^ (s & 7)) << 4)) + (e & 7) * 2;
    }
    char* const sHb = reinterpret_cast<char*>(sH);

    #pragma unroll 2
    for (int step = 0; step < LL; ++step) {
        const int cb  = (step & 1) << 12;   // current buf base: 0 or 4096
        const int nb_ = cb ^ 4096;          // next buf base

        // 1. convert in-flight f32 x_t -> bf16 A-frags (RNE, == old cvt_table)
        short8 axA0 = pack_frag(pA0, pA1);
        short8 axA1 = pack_frag(pA2, pA3);
        short8 axB0 = pack_frag(pB0, pB1);
        short8 axB1 = pack_frag(pB2, pB3);

        // 2. issue x prefetch for step+1 (stays in flight across the barrier)
        pA0 = *reinterpret_cast<const float4*>(tblf + (size_t)idA * 256);
        pA1 = *reinterpret_cast<const float4*>(tblf + (size_t)idA * 256 + 16);
        pA2 = *reinterpret_cast<const float4*>(tblf + (size_t)idA * 256 + 128);
        pA3 = *reinterpret_cast<const float4*>(tblf + (size_t)idA * 256 + 144);
        pB0 = *reinterpret_cast<const float4*>(tblf + (size_t)idB * 256);
        pB1 = *reinterpret_cast<const float4*>(tblf + (size_t)idB * 256 + 16);
        pB2 = *reinterpret_cast<const float4*>(tblf + (size_t)idB * 256 + 128);
        pB3 = *reinterpret_cast<const float4*>(tblf + (size_t)idB * 256 + 144);
        {
            const int s2 = (step + 2 < LL) ? (step + 2) : (LL - 1);
            idA = sIdx[ibA + s2]; idB = sIdx[ibB + s2];
        }

        // 3. read h A-frags for both chains (swizzled, conflict-free)
        short8 ahA0 = *reinterpret_cast<const short8*>(sHb + cb + offA0);
        short8 ahA1 = *reinterpret_cast<const short8*>(sHb + cb + offA1);
        short8 ahB0 = *reinterpret_cast<const short8*>(sHb + cb + 2048 + offA0);
        short8 ahB1 = *reinterpret_cast<const short8*>(sHb + cb + 2048 + offA1);

        // 4. acc = scaled_bias + x @ sWih^T + h @ sWhh^T  (2 independent chains)
        v4f accA[4], accB[4];
        #pragma unroll
        for (int g = 0; g < 4; ++g) {
            v4f a; a[0] = bias[g]; a[1] = bias[g]; a[2] = bias[g]; a[3] = bias[g];
            accA[g] = a; accB[g] = a;
        }
        #pragma unroll
        for (int g = 0; g < 4; ++g) {
            accA[g] = __builtin_amdgcn_mfma_f32_16x16x32_bf16(axA0, Bf[0][g][0], accA[g], 0, 0, 0);
            accA[g] = __builtin_amdgcn_mfma_f32_16x16x32_bf16(axA1, Bf[0][g][1], accA[g], 0, 0, 0);
            accA[g] = __builtin_amdgcn_mfma_f32_16x16x32_bf16(ahA0, Bf[1][g][0], accA[g], 0, 0, 0);
            accA[g] = __builtin_amdgcn_mfma_f32_16x16x32_bf16(ahA1, Bf[1][g][1], accA[g], 0, 0, 0);
        }
        #pragma unroll
        for (int g = 0; g < 4; ++g) {
            accB[g] = __builtin_amdgcn_mfma_f32_16x16x32_bf16(axB0, Bf[0][g][0], accB[g], 0, 0, 0);
            accB[g] = __builtin_amdgcn_mfma_f32_16x16x32_bf16(axB1, Bf[0][g][1], accB[g], 0, 0, 0);
            accB[g] = __builtin_amdgcn_mfma_f32_16x16x32_bf16(ahB0, Bf[1][g][0], accB[g], 0, 0, 0);
            accB[g] = __builtin_amdgcn_mfma_f32_16x16x32_bf16(ahB1, Bf[1][g][1], accB[g], 0, 0, 0);
        }

        // 5. gate nonlinearities (exp2 args straight from MFMA) + h writes
        {
            char* SH = sHb + nb_;
            #pragma unroll
            for (int r = 0; r < 4; ++r) {
                const float si = rcpf(1.0f + exp2_fast(accA[0][r]));
                const float sf = rcpf(1.0f + exp2_fast(accA[1][r]));
                const float tg = fmaf(-2.0f, rcpf(1.0f + exp2_fast(accA[2][r])), 1.0f);
                const float so = rcpf(1.0f + exp2_fast(accA[3][r]));
                const float cc = fmaf(sf, cA[r], si * tg);
                cA[r] = cc;
                hA[r] = so * fmaf(-2.0f, rcpf(1.0f + exp2_fast(cc * (2.0f * L2E))), 1.0f);
            }
            const unsigned a01 = cvt_pk_bf16(hA[0], hA[1]);
            const unsigned a23 = cvt_pk_bf16(hA[2], hA[3]);
            *reinterpret_cast<short*>(SH + hw_off[0]) = (short)(a01 & 0xFFFF);
            *reinterpret_cast<short*>(SH + hw_off[1]) = (short)(a01 >> 16);
            *reinterpret_cast<short*>(SH + hw_off[2]) = (short)(a23 & 0xFFFF);
            *reinterpret_cast<short*>(SH + hw_off[3]) = (short)(a23 >> 16);
            SH += 2048;
            #pragma unroll
            for (int r = 0; r < 4; ++r) {
                const float si = rcpf(1.0f + exp2_fast(accB[0][r]));
                const float sf = rcpf(1.0f + exp2_fast(accB[1][r]));
                const float tg = fmaf(-2.0f, rcpf(1.0f + exp2_fast(accB[2][r])), 1.0f);
                const float so = rcpf(1.0f + exp2_fast(accB[3][r]));
                const float cc = fmaf(sf, cB[r], si * tg);
                cB[r] = cc;
                hB[r] = so * fmaf(-2.0f, rcpf(1.0f + exp2_fast(cc * (2.0f * L2E))), 1.0f);
            }
            const unsigned b01 = cvt_pk_bf16(hB[0], hB[1]);
            const unsigned b23 = cvt_pk_bf16(hB[2], hB[3]);
            *reinterpret_cast<short*>(SH + hw_off[0]) = (short)(b01 & 0xFFFF);
            *reinterpret_cast<short*>(SH + hw_off[1]) = (short)(b01 >> 16);
            *reinterpret_cast<short*>(SH + hw_off[2]) = (short)(b23 & 0xFFFF);
            *reinterpret_cast<short*>(SH + hw_off[3]) = (short)(b23 >> 16);
        }

        // 6. LDS-only barrier (x prefetch loads stay in flight)
        block_sync_lds();
    }

    // --- write final h -> m_act [16384][64] f32 (chain A then B)
    #pragma unroll
    for (int r = 0; r < 4; ++r) {
        const int s = lb * 4 + r;
        m_act[((size_t)(blk * 32 + s)) * EE + w * 16 + lr]      = hA[r];
        m_act[((size_t)(blk * 32 + 16 + s)) * EE + w * 16 + lr] = hB[r];
    }
}

// ---------------------------------------------------------------------------
// Kernel B: GCN gather + linear/relu + fuse + PNA reduce + MLPs + predict.
// One block per batch element b (1024 blocks x 256 threads).
// Round 11: neighborhood gather restructured from a 4-deep serial load-add
// chain to 33 independent loads + tree sum (latency fully pipelined).
// ---------------------------------------------------------------------------
__global__ __launch_bounds__(256)
void post_kernel(const int* __restrict__ members, const int* __restrict__ neighbors,
                 const int* __restrict__ act_inputs,
                 const float* __restrict__ act_table, const float* __restrict__ user_table,
                 const float* __restrict__ gcn_W, const float* __restrict__ gcn_b,
                 const float* __restrict__ pna_W1, const float* __restrict__ pna_b1,
                 const float* __restrict__ pna_W2, const float* __restrict__ pna_b2,
                 const float* __restrict__ pna_W3, const float* __restrict__ pna_b3,
                 const float* __restrict__ pred_W1, const float* __restrict__ pred_b1,
                 const float* __restrict__ pred_W2, const float* __restrict__ pred_b2,
                 const float* __restrict__ m_act, float* __restrict__ out)
{
    __shared__ float sWg[64][64];    // gcn_W transposed [k][e]
    __shared__ float sAgg[16][64];
    __shared__ float sFus[16][64];
    __shared__ float sActe[64];
    __shared__ float sFeats[256];
    __shared__ float sPart[4][64];
    __shared__ float sH1[64];
    __shared__ float sH2[64];
    __shared__ float sGrp[64];
    __shared__ float sHH[8];

    const int t  = threadIdx.x;
    const int b  = blockIdx.x;
    const int e  = t & 63;
    const int mq = t >> 6;   // 0..3 (wave id)

    {
        const int kq = (t & 15) * 4;
        const int er = t >> 4;   // 0..15
        #pragma unroll
        for (int rep = 0; rep < 4; ++rep) {
            int row = rep * 16 + er;
            float4 v = *reinterpret_cast<const float4*>(&gcn_W[row * 64 + kq]);
            sWg[kq + 0][row] = v.x;
            sWg[kq + 1][row] = v.y;
            sWg[kq + 2][row] = v.z;
            sWg[kq + 3][row] = v.w;
        }
    }
    if (t < 64) sActe[t] = act_table[(size_t)act_inputs[b] * EE + t];

    // neighborhood aggregation: 33 independent loads in flight, tree sum
    for (int mb = 0; mb < 4; ++mb) {
        int m = mb * 4 + mq;
        int base = b * MM + m;
        const int* nb = &neighbors[base * KK];
        float v[KK + 1];
        v[KK] = user_table[(size_t)members[base] * EE + e];
        #pragma unroll
        for (int kk = 0; kk < KK; ++kk)
            v[kk] = user_table[(size_t)nb[kk] * EE + e];
        // pairwise tree reduction over 33 values
        #pragma unroll
        for (int st = 1; st < KK; st <<= 1)
            #pragma unroll
            for (int kk = 0; kk + st < KK; kk += 2 * st)
                v[kk] += v[kk + st];
        sAgg[m][e] = (v[0] + v[KK]) * (1.0f / 33.0f);
    }
    __syncthreads();

    for (int mb = 0; mb < 4; ++mb) {
        int m = mb * 4 + mq;
        float a = gcn_b[e];
        #pragma unroll
        for (int k = 0; k < 64; ++k) a = fmaf(sAgg[m][k], sWg[k][e], a);
        a = fmaxf(a, 0.0f);
        sFus[m][e] = m_act[((size_t)(b * MM + m)) * EE + e] + a;
    }
    __syncthreads();

    if (t < 64) {
        float mn = 0.0f, mx = -INFINITY;
        #pragma unroll
        for (int m = 0; m < MM; ++m) { float v = sFus[m][t]; mn += v; mx = fmaxf(mx, v); }
        mn *= (1.0f / 16.0f);
        sFeats[t] = mn; sFeats[64 + t] = mx; sFeats[128 + t] = mn; sFeats[192 + t] = mx;
    }
    __syncthreads();

    {
        float p = 0.0f;
        #pragma unroll 8
        for (int kk = 0; kk < 64; ++kk) {
            int k = mq * 64 + kk;
            p = fmaf(sFeats[k], pna_W1[(size_t)k * 64 + e], p);
        }
        sPart[mq][e] = p;
    }
    __syncthreads();
    if (t < 64) sH1[t] = fmaxf(pna_b1[t] + sPart[0][t] + sPart[1][t] + sPart[2][t] + sPart[3][t], 0.0f);
    __syncthreads();

    {
        float p = 0.0f;
        #pragma unroll
        for (int kk = 0; kk < 16; ++kk) {
            int k = mq * 16 + kk;
            p = fmaf(sH1[k], pna_W2[(size_t)k * 64 + e], p);
        }
        sPart[mq][e] = p;
    }
    __syncthreads();
    if (t < 64) sH2[t] = fmaxf(pna_b2[t] + sPart[0][t] + sPart[1][t] + sPart[2][t] + sPart[3][t], 0.0f);
    __syncthreads();

    {
        float p = 0.0f;
        #pragma unroll
        for (int kk = 0; kk < 16; ++kk) {
            int k = mq * 16 + kk;
            p = fmaf(sH2[k], pna_W3[(size_t)k * 64 + e], p);
        }
        sPart[mq][e] = p;
    }
    __syncthreads();
    if (t < 64) sGrp[t] = pna_b3[t] + sPart[0][t] + sPart[1][t] + sPart[2][t] + sPart[3][t];
    __syncthreads();

    if (t < 8) {
        float a = pred_b1[t];
        for (int k = 0; k < 192; ++k) {
            float cv = (k < 64) ? sGrp[k] * sActe[k]
                                : ((k < 128) ? sGrp[k - 64] : sActe[k - 128]);
            a = fmaf(cv, pred_W1[k * 8 + t], a);
        }
        sHH[t] = fmaxf(a, 0.0f);
    }
    __syncthreads();
    if (t == 0) {
        float y = pred_b2[0];
        #pragma unroll
        for (int j = 0; j < 8; ++j) y = fmaf(sHH[j], pred_W2[j], y);
        out[b] = 1.0f / (1.0f + expf(-y));
    }
}

extern "C" void kernel_launch(void* const* d_in, const int* in_sizes, int n_in,
                              void* d_out, int out_size, void* d_ws, size_t ws_size,
                              hipStream_t stream) {
    const int*   members    = (const int*)d_in[0];
    const int*   neighbors  = (const int*)d_in[1];
    const int*   act_inputs = (const int*)d_in[2];
    const int*   act_seqs   = (const int*)d_in[3];
    const float* act_table  = (const float*)d_in[4];
    const float* user_table = (const float*)d_in[5];
    const float* W_ih       = (const float*)d_in[6];
    const float* W_hh       = (const float*)d_in[7];
    const float* b_ih       = (const float*)d_in[8];
    const float* b_hh       = (const float*)d_in[9];
    const float* gcn_W      = (const float*)d_in[10];
    const float* gcn_b      = (const float*)d_in[11];
    const float* pna_W1     = (const float*)d_in[12];
    const float* pna_b1     = (const float*)d_in[13];
    const float* pna_W2     = (const float*)d_in[14];
    const float* pna_b2     = (const float*)d_in[15];
    const float* pna_W3     = (const float*)d_in[16];
    const float* pna_b3     = (const float*)d_in[17];
    const float* pred_W1    = (const float*)d_in[18];
    const float* pred_b1    = (const float*)d_in[19];
    const float* pred_W2    = (const float*)d_in[20];
    const float* pred_b2    = (const float*)d_in[21];

    float* m_act = (float*)d_ws;   // [16384][64] f32 = 4 MB scratch

    lstm_mfma<<<dim3(512), dim3(256), 0, stream>>>(
        act_seqs, act_table, W_ih, W_hh, b_ih, b_hh, m_act);

    post_kernel<<<dim3(BB), dim3(256), 0, stream>>>(
        members, neighbors, act_inputs, act_table, user_table,
        gcn_W, gcn_b, pna_W1, pna_b1, pna_W2, pna_b2, pna_W3, pna_b3,
        pred_W1, pred_b1, pred_W2, pred_b2, m_act, (float*)d_out);
}

// Round 12
// 153.437 us; speedup vs baseline: 1.1639x; 1.1639x over previous
//
#include <hip/hip_runtime.h>
#include <hip/hip_bf16.h>
#include <math.h>

// Problem constants (match reference)
#define BB   1024
#define MM   16
#define KK   32
#define LL   50
#define EE   64
#define NACT 100000

typedef __attribute__((ext_vector_type(8))) short short8;
typedef float v4f __attribute__((ext_vector_type(4)));

__device__ __forceinline__ float rcpf(float x) { return __builtin_amdgcn_rcpf(x); }
// native 2^x (v_exp_f32 IS exp2)
__device__ __forceinline__ float exp2_fast(float x) {
    float r;
    asm("v_exp_f32 %0, %1" : "=v"(r) : "v"(x));
    return r;
}

// packed f32x2 -> bf16x2 (lo->low16, hi->high16), RNE
__device__ __forceinline__ unsigned cvt_pk_bf16(float lo, float hi) {
    unsigned r;
    asm("v_cvt_pk_bf16_f32 %0, %1, %2" : "=v"(r) : "v"(lo), "v"(hi));
    return r;
}

// Block-wide barrier that does NOT drain vmcnt: LDS writes are made visible
// (lgkmcnt(0)) but global prefetch loads stay in flight across the barrier.
__device__ __forceinline__ void block_sync_lds() {
    __builtin_amdgcn_sched_barrier(0);
    asm volatile("s_waitcnt lgkmcnt(0)" ::: "memory");
    __builtin_amdgcn_s_barrier();
    __builtin_amdgcn_sched_barrier(0);
}

// ---------------------------------------------------------------------------
// Pre-pass: act_table f32 -> bf16 (row-major, same layout). 8 floats/thread.
// (r11 tried deleting this and gathering f32 directly in the LSTM: lstm FETCH
// doubled 40->89 MB and dur went 95.5->117.5 us. The bf16 table halves gather
// bytes and L2 footprint; keep it.)
// ---------------------------------------------------------------------------
__global__ __launch_bounds__(256)
void cvt_table(const float* __restrict__ src, unsigned* __restrict__ dst)
{
    const int i = blockIdx.x * 256 + threadIdx.x;          // unit = 8 floats
    if (i < (NACT * EE) / 8) {
        const float4* s = reinterpret_cast<const float4*>(src) + (size_t)i * 2;
        float4 a = s[0], b = s[1];
        uint4 o;
        o.x = cvt_pk_bf16(a.x, a.y);
        o.y = cvt_pk_bf16(a.z, a.w);
        o.z = cvt_pk_bf16(b.x, b.y);
        o.w = cvt_pk_bf16(b.z, b.w);
        reinterpret_cast<uint4*>(dst)[i] = o;
    }
}

// ---------------------------------------------------------------------------
// MFMA LSTM, dual-chain + exp2 fold (r10 structure, best measured: 95.5 us):
// 512 blocks x 256 threads; 32 seqs/block as two independent 16-seq chains
// per wave (2x ILP inside each wave). Weight columns & biases pre-scaled by
// -log2e (i,f,o) / +2*log2e (g) so MFMA output feeds v_exp_f32 (=2^x)
// directly:  sigma(pre) = rcp(1+exp2(acc)), tanh(pre) = 1-2*rcp(1+exp2(acc)).
// Weights in registers (64 VGPR); h via swizzled bf16 LDS double buffer;
// x A-frags prefetched top-of-step from the bf16 table, left in flight
// across the non-draining barrier; step loop unrolled 2x.
// ---------------------------------------------------------------------------
__global__ __launch_bounds__(256, 2)
void lstm_mfma(const int* __restrict__ act_seqs, const unsigned short* __restrict__ act_bf,
               const float* __restrict__ W_ih, const float* __restrict__ W_hh,
               const float* __restrict__ b_ih, const float* __restrict__ b_hh,
               float* __restrict__ m_act)
{
    __shared__ __align__(16) short sH[4][1024];   // tile = buf*2 + chain; [16][64] bf16 swizzled
    __shared__ int sIdx[32 * LL];

    const int t    = threadIdx.x;
    const int blk  = blockIdx.x;
    const int lane = t & 63;
    const int w    = t >> 6;        // wave id = e-block (0..3)
    const int lr   = lane & 15;     // A row (seq) / B,D col selector
    const int lb   = lane >> 4;     // k-block / D row-block selector

    // --- this block's indices (contiguous 1600 ints, coalesced)
    for (int i = t; i < 32 * LL; i += 256) sIdx[i] = act_seqs[blk * (32 * LL) + i];

    // per-gate exp2 fold scales (i,f,o: -log2e; g: +2*log2e)
    const float L2E = 1.44269504088896f;
    float gscale[4];
    gscale[0] = -L2E; gscale[1] = -L2E; gscale[2] = 2.0f * L2E; gscale[3] = -L2E;

    // --- weights -> register B-frags, SCALED. gates = in @ W^T => B[k][j]=W[j][k].
    // lane holds col j = g*64 + 16w + lr, k = 32*ks + 8*lb + i.
    short8 Bf[2][4][2];   // [mat(ih,hh)][gate][ks]
    #pragma unroll
    for (int mat = 0; mat < 2; ++mat) {
        const float* W = mat ? W_hh : W_ih;
        #pragma unroll
        for (int g = 0; g < 4; ++g) {
            const int j = g * 64 + w * 16 + lr;
            const float sc = gscale[g];
            #pragma unroll
            for (int ks = 0; ks < 2; ++ks) {
                const float4* p = reinterpret_cast<const float4*>(&W[(size_t)j * 64 + ks * 32 + lb * 8]);
                float4 v0 = p[0], v1 = p[1];
                uint4 o;
                o.x = cvt_pk_bf16(sc * v0.x, sc * v0.y);
                o.y = cvt_pk_bf16(sc * v0.z, sc * v0.w);
                o.z = cvt_pk_bf16(sc * v1.x, sc * v1.y);
                o.w = cvt_pk_bf16(sc * v1.z, sc * v1.w);
                Bf[mat][g][ks] = __builtin_bit_cast(short8, o);
            }
        }
    }
    float bias[4];
    #pragma unroll
    for (int g = 0; g < 4; ++g) {
        const int j = g * 64 + w * 16 + lr;
        bias[g] = gscale[g] * (b_ih[j] + b_hh[j]);
    }

    float hA[4], cA[4], hB[4], cB[4];
    #pragma unroll
    for (int r = 0; r < 4; ++r) { hA[r] = 0.0f; cA[r] = 0.0f; hB[r] = 0.0f; cB[r] = 0.0f; }

    // zero buf0 (tiles 0,1 = 4096 B = 256 x uint4)
    reinterpret_cast<uint4*>(sH)[t] = make_uint4(0u, 0u, 0u, 0u);
    __syncthreads();   // sIdx + sH buf0 visible (once, outside loop)

    // --- x gather: lane's frag = bytes [id*128 + lb*16] and +64.
    const char* tbl8 = reinterpret_cast<const char*>(act_bf) + lb * 16;
    const int ibA = lr * LL;           // chain A: seq lr
    const int ibB = (16 + lr) * LL;    // chain B: seq 16+lr

    int idA = sIdx[ibA + 0], idB = sIdx[ibB + 0];
    short8 axA0 = *reinterpret_cast<const short8*>(tbl8 + (size_t)idA * 128);
    short8 axA1 = *reinterpret_cast<const short8*>(tbl8 + (size_t)idA * 128 + 64);
    short8 axB0 = *reinterpret_cast<const short8*>(tbl8 + (size_t)idB * 128);
    short8 axB1 = *reinterpret_cast<const short8*>(tbl8 + (size_t)idB * 128 + 64);
    idA = sIdx[ibA + 1]; idB = sIdx[ibB + 1];

    // LDS byte offsets (loop-invariant)
    const int offA0 = lr * 128 + ((lb ^ (lr & 7)) << 4);
    const int offA1 = lr * 128 + (((lb + 4) ^ (lr & 7)) << 4);
    int hw_off[4];
    #pragma unroll
    for (int r = 0; r < 4; ++r) {
        const int s = lb * 4 + r, e = w * 16 + lr;
        hw_off[r] = s * 128 + ((((e >> 3) ^ (s & 7)) << 4)) + (e & 7) * 2;
    }
    char* const sHb = reinterpret_cast<char*>(sH);

    #pragma unroll 2
    for (int step = 0; step < LL; ++step) {
        const int cb  = (step & 1) << 12;   // current buf base: 0 or 4096
        const int nb_ = cb ^ 4096;          // next buf base

        // 1. issue x prefetch for step+1 (stays in flight across the barrier)
        short8 nxA0 = *reinterpret_cast<const short8*>(tbl8 + (size_t)idA * 128);
        short8 nxA1 = *reinterpret_cast<const short8*>(tbl8 + (size_t)idA * 128 + 64);
        short8 nxB0 = *reinterpret_cast<const short8*>(tbl8 + (size_t)idB * 128);
        short8 nxB1 = *reinterpret_cast<const short8*>(tbl8 + (size_t)idB * 128 + 64);
        {
            const int s2 = (step + 2 < LL) ? (step + 2) : (LL - 1);
            idA = sIdx[ibA + s2]; idB = sIdx[ibB + s2];
        }

        // 2. read h A-frags for both chains (swizzled, conflict-free)
        short8 ahA0 = *reinterpret_cast<const short8*>(sHb + cb + offA0);
        short8 ahA1 = *reinterpret_cast<const short8*>(sHb + cb + offA1);
        short8 ahB0 = *reinterpret_cast<const short8*>(sHb + cb + 2048 + offA0);
        short8 ahB1 = *reinterpret_cast<const short8*>(sHb + cb + 2048 + offA1);

        // 3. acc = scaled_bias + x @ sWih^T + h @ sWhh^T  (2 independent chains)
        v4f accA[4], accB[4];
        #pragma unroll
        for (int g = 0; g < 4; ++g) {
            v4f a; a[0] = bias[g]; a[1] = bias[g]; a[2] = bias[g]; a[3] = bias[g];
            accA[g] = a; accB[g] = a;
        }
        #pragma unroll
        for (int g = 0; g < 4; ++g) {
            accA[g] = __builtin_amdgcn_mfma_f32_16x16x32_bf16(axA0, Bf[0][g][0], accA[g], 0, 0, 0);
            accA[g] = __builtin_amdgcn_mfma_f32_16x16x32_bf16(axA1, Bf[0][g][1], accA[g], 0, 0, 0);
            accA[g] = __builtin_amdgcn_mfma_f32_16x16x32_bf16(ahA0, Bf[1][g][0], accA[g], 0, 0, 0);
            accA[g] = __builtin_amdgcn_mfma_f32_16x16x32_bf16(ahA1, Bf[1][g][1], accA[g], 0, 0, 0);
        }
        #pragma unroll
        for (int g = 0; g < 4; ++g) {
            accB[g] = __builtin_amdgcn_mfma_f32_16x16x32_bf16(axB0, Bf[0][g][0], accB[g], 0, 0, 0);
            accB[g] = __builtin_amdgcn_mfma_f32_16x16x32_bf16(axB1, Bf[0][g][1], accB[g], 0, 0, 0);
            accB[g] = __builtin_amdgcn_mfma_f32_16x16x32_bf16(ahB0, Bf[1][g][0], accB[g], 0, 0, 0);
            accB[g] = __builtin_amdgcn_mfma_f32_16x16x32_bf16(ahB1, Bf[1][g][1], accB[g], 0, 0, 0);
        }

        // 4. gate nonlinearities (exp2 args straight from MFMA) + h writes
        {
            char* SH = sHb + nb_;
            #pragma unroll
            for (int r = 0; r < 4; ++r) {
                const float si = rcpf(1.0f + exp2_fast(accA[0][r]));
                const float sf = rcpf(1.0f + exp2_fast(accA[1][r]));
                const float tg = fmaf(-2.0f, rcpf(1.0f + exp2_fast(accA[2][r])), 1.0f);
                const float so = rcpf(1.0f + exp2_fast(accA[3][r]));
                const float cc = fmaf(sf, cA[r], si * tg);
                cA[r] = cc;
                hA[r] = so * fmaf(-2.0f, rcpf(1.0f + exp2_fast(cc * (2.0f * L2E))), 1.0f);
            }
            const unsigned a01 = cvt_pk_bf16(hA[0], hA[1]);
            const unsigned a23 = cvt_pk_bf16(hA[2], hA[3]);
            *reinterpret_cast<short*>(SH + hw_off[0]) = (short)(a01 & 0xFFFF);
            *reinterpret_cast<short*>(SH + hw_off[1]) = (short)(a01 >> 16);
            *reinterpret_cast<short*>(SH + hw_off[2]) = (short)(a23 & 0xFFFF);
            *reinterpret_cast<short*>(SH + hw_off[3]) = (short)(a23 >> 16);
            SH += 2048;
            #pragma unroll
            for (int r = 0; r < 4; ++r) {
                const float si = rcpf(1.0f + exp2_fast(accB[0][r]));
                const float sf = rcpf(1.0f + exp2_fast(accB[1][r]));
                const float tg = fmaf(-2.0f, rcpf(1.0f + exp2_fast(accB[2][r])), 1.0f);
                const float so = rcpf(1.0f + exp2_fast(accB[3][r]));
                const float cc = fmaf(sf, cB[r], si * tg);
                cB[r] = cc;
                hB[r] = so * fmaf(-2.0f, rcpf(1.0f + exp2_fast(cc * (2.0f * L2E))), 1.0f);
            }
            const unsigned b01 = cvt_pk_bf16(hB[0], hB[1]);
            const unsigned b23 = cvt_pk_bf16(hB[2], hB[3]);
            *reinterpret_cast<short*>(SH + hw_off[0]) = (short)(b01 & 0xFFFF);
            *reinterpret_cast<short*>(SH + hw_off[1]) = (short)(b01 >> 16);
            *reinterpret_cast<short*>(SH + hw_off[2]) = (short)(b23 & 0xFFFF);
            *reinterpret_cast<short*>(SH + hw_off[3]) = (short)(b23 >> 16);
        }

        // 5. LDS-only barrier (x prefetch loads stay in flight)
        block_sync_lds();

        // 6. roll prefetch regs (unroll-2 lets the allocator rename these)
        axA0 = nxA0; axA1 = nxA1; axB0 = nxB0; axB1 = nxB1;
    }

    // --- write final h -> m_act [16384][64] f32 (chain A then B)
    #pragma unroll
    for (int r = 0; r < 4; ++r) {
        const int s = lb * 4 + r;
        m_act[((size_t)(blk * 32 + s)) * EE + w * 16 + lr]      = hA[r];
        m_act[((size_t)(blk * 32 + 16 + s)) * EE + w * 16 + lr] = hB[r];
    }
}

// ---------------------------------------------------------------------------
// Kernel B: GCN gather + linear/relu + fuse + PNA reduce + MLPs + predict.
// One block per batch element b (1024 blocks x 256 threads).
// Round 12: neighborhood gather uses 8 independent partial accumulators
// (8 loads in flight per group) instead of a single serial add chain.
// (r11's 33-element tree-sum array regressed; this is the minimal form.)
// ---------------------------------------------------------------------------
__global__ __launch_bounds__(256)
void post_kernel(const int* __restrict__ members, const int* __restrict__ neighbors,
                 const int* __restrict__ act_inputs,
                 const float* __restrict__ act_table, const float* __restrict__ user_table,
                 const float* __restrict__ gcn_W, const float* __restrict__ gcn_b,
                 const float* __restrict__ pna_W1, const float* __restrict__ pna_b1,
                 const float* __restrict__ pna_W2, const float* __restrict__ pna_b2,
                 const float* __restrict__ pna_W3, const float* __restrict__ pna_b3,
                 const float* __restrict__ pred_W1, const float* __restrict__ pred_b1,
                 const float* __restrict__ pred_W2, const float* __restrict__ pred_b2,
                 const float* __restrict__ m_act, float* __restrict__ out)
{
    __shared__ float sWg[64][64];    // gcn_W transposed [k][e]
    __shared__ float sAgg[16][64];
    __shared__ float sFus[16][64];
    __shared__ float sActe[64];
    __shared__ float sFeats[256];
    __shared__ float sPart[4][64];
    __shared__ float sH1[64];
    __shared__ float sH2[64];
    __shared__ float sGrp[64];
    __shared__ float sHH[8];

    const int t  = threadIdx.x;
    const int b  = blockIdx.x;
    const int e  = t & 63;
    const int mq = t >> 6;   // 0..3 (wave id)

    {
        const int kq = (t & 15) * 4;
        const int er = t >> 4;   // 0..15
        #pragma unroll
        for (int rep = 0; rep < 4; ++rep) {
            int row = rep * 16 + er;
            float4 v = *reinterpret_cast<const float4*>(&gcn_W[row * 64 + kq]);
            sWg[kq + 0][row] = v.x;
            sWg[kq + 1][row] = v.y;
            sWg[kq + 2][row] = v.z;
            sWg[kq + 3][row] = v.w;
        }
    }
    if (t < 64) sActe[t] = act_table[(size_t)act_inputs[b] * EE + t];

    // neighborhood aggregation: 8 independent partial sums (8 loads in flight)
    for (int mb = 0; mb < 4; ++mb) {
        int m = mb * 4 + mq;
        int base = b * MM + m;
        const int* nb = &neighbors[base * KK];
        float p0, p1, p2, p3, p4, p5, p6, p7;
        p0 = user_table[(size_t)members[base] * EE + e];
        p1 = p2 = p3 = p4 = p5 = p6 = p7 = 0.0f;
        #pragma unroll
        for (int kk = 0; kk < KK; kk += 8) {
            float v0 = user_table[(size_t)nb[kk + 0] * EE + e];
            float v1 = user_table[(size_t)nb[kk + 1] * EE + e];
            float v2 = user_table[(size_t)nb[kk + 2] * EE + e];
            float v3 = user_table[(size_t)nb[kk + 3] * EE + e];
            float v4 = user_table[(size_t)nb[kk + 4] * EE + e];
            float v5 = user_table[(size_t)nb[kk + 5] * EE + e];
            float v6 = user_table[(size_t)nb[kk + 6] * EE + e];
            float v7 = user_table[(size_t)nb[kk + 7] * EE + e];
            p0 += v0; p1 += v1; p2 += v2; p3 += v3;
            p4 += v4; p5 += v5; p6 += v6; p7 += v7;
        }
        sAgg[m][e] = ((p0 + p1) + (p2 + p3) + ((p4 + p5) + (p6 + p7))) * (1.0f / 33.0f);
    }
    __syncthreads();

    for (int mb = 0; mb < 4; ++mb) {
        int m = mb * 4 + mq;
        float a = gcn_b[e];
        #pragma unroll
        for (int k = 0; k < 64; ++k) a = fmaf(sAgg[m][k], sWg[k][e], a);
        a = fmaxf(a, 0.0f);
        sFus[m][e] = m_act[((size_t)(b * MM + m)) * EE + e] + a;
    }
    __syncthreads();

    if (t < 64) {
        float mn = 0.0f, mx = -INFINITY;
        #pragma unroll
        for (int m = 0; m < MM; ++m) { float v = sFus[m][t]; mn += v; mx = fmaxf(mx, v); }
        mn *= (1.0f / 16.0f);
        sFeats[t] = mn; sFeats[64 + t] = mx; sFeats[128 + t] = mn; sFeats[192 + t] = mx;
    }
    __syncthreads();

    {
        float p = 0.0f;
        #pragma unroll 8
        for (int kk = 0; kk < 64; ++kk) {
            int k = mq * 64 + kk;
            p = fmaf(sFeats[k], pna_W1[(size_t)k * 64 + e], p);
        }
        sPart[mq][e] = p;
    }
    __syncthreads();
    if (t < 64) sH1[t] = fmaxf(pna_b1[t] + sPart[0][t] + sPart[1][t] + sPart[2][t] + sPart[3][t], 0.0f);
    __syncthreads();

    {
        float p = 0.0f;
        #pragma unroll
        for (int kk = 0; kk < 16; ++kk) {
            int k = mq * 16 + kk;
            p = fmaf(sH1[k], pna_W2[(size_t)k * 64 + e], p);
        }
        sPart[mq][e] = p;
    }
    __syncthreads();
    if (t < 64) sH2[t] = fmaxf(pna_b2[t] + sPart[0][t] + sPart[1][t] + sPart[2][t] + sPart[3][t], 0.0f);
    __syncthreads();

    {
        float p = 0.0f;
        #pragma unroll
        for (int kk = 0; kk < 16; ++kk) {
            int k = mq * 16 + kk;
            p = fmaf(sH2[k], pna_W3[(size_t)k * 64 + e], p);
        }
        sPart[mq][e] = p;
    }
    __syncthreads();
    if (t < 64) sGrp[t] = pna_b3[t] + sPart[0][t] + sPart[1][t] + sPart[2][t] + sPart[3][t];
    __syncthreads();

    if (t < 8) {
        float a = pred_b1[t];
        for (int k = 0; k < 192; ++k) {
            float cv = (k < 64) ? sGrp[k] * sActe[k]
                                : ((k < 128) ? sGrp[k - 64] : sActe[k - 128]);
            a = fmaf(cv, pred_W1[k * 8 + t], a);
        }
        sHH[t] = fmaxf(a, 0.0f);
    }
    __syncthreads();
    if (t == 0) {
        float y = pred_b2[0];
        #pragma unroll
        for (int j = 0; j < 8; ++j) y = fmaf(sHH[j], pred_W2[j], y);
        out[b] = 1.0f / (1.0f + expf(-y));
    }
}

extern "C" void kernel_launch(void* const* d_in, const int* in_sizes, int n_in,
                              void* d_out, int out_size, void* d_ws, size_t ws_size,
                              hipStream_t stream) {
    const int*   members    = (const int*)d_in[0];
    const int*   neighbors  = (const int*)d_in[1];
    const int*   act_inputs = (const int*)d_in[2];
    const int*   act_seqs   = (const int*)d_in[3];
    const float* act_table  = (const float*)d_in[4];
    const float* user_table = (const float*)d_in[5];
    const float* W_ih       = (const float*)d_in[6];
    const float* W_hh       = (const float*)d_in[7];
    const float* b_ih       = (const float*)d_in[8];
    const float* b_hh       = (const float*)d_in[9];
    const float* gcn_W      = (const float*)d_in[10];
    const float* gcn_b      = (const float*)d_in[11];
    const float* pna_W1     = (const float*)d_in[12];
    const float* pna_b1     = (const float*)d_in[13];
    const float* pna_W2     = (const float*)d_in[14];
    const float* pna_b2     = (const float*)d_in[15];
    const float* pna_W3     = (const float*)d_in[16];
    const float* pna_b3     = (const float*)d_in[17];
    const float* pred_W1    = (const float*)d_in[18];
    const float* pred_b1    = (const float*)d_in[19];
    const float* pred_W2    = (const float*)d_in[20];
    const float* pred_b2    = (const float*)d_in[21];

    float*          m_act  = (float*)d_ws;                         // 4 MB
    unsigned short* act_bf = (unsigned short*)((char*)d_ws + (size_t)BB * MM * EE * 4);  // 12.8 MB

    cvt_table<<<dim3((NACT * EE / 8 + 255) / 256), dim3(256), 0, stream>>>(
        act_table, (unsigned*)act_bf);

    lstm_mfma<<<dim3(512), dim3(256), 0, stream>>>(
        act_seqs, act_bf, W_ih, W_hh, b_ih, b_hh, m_act);

    post_kernel<<<dim3(BB), dim3(256), 0, stream>>>(
        members, neighbors, act_inputs, act_table, user_table,
        gcn_W, gcn_b, pna_W1, pna_b1, pna_W2, pna_b2, pna_W3, pna_b3,
        pred_W1, pred_b1, pred_W2, pred_b2, m_act, (float*)d_out);
}

// Round 13
// 142.884 us; speedup vs baseline: 1.2499x; 1.0739x over previous
//
#include <hip/hip_runtime.h>
#include <hip/hip_bf16.h>
#include <math.h>

// Problem constants (match reference)
#define BB   1024
#define MM   16
#define KK   32
#define LL   50
#define EE   64
#define NACT 100000

typedef __attribute__((ext_vector_type(8))) short short8;
typedef float v4f __attribute__((ext_vector_type(4)));

__device__ __forceinline__ float rcpf(float x) { return __builtin_amdgcn_rcpf(x); }
// native 2^x (v_exp_f32 IS exp2)
__device__ __forceinline__ float exp2_fast(float x) {
    float r;
    asm("v_exp_f32 %0, %1" : "=v"(r) : "v"(x));
    return r;
}

// packed f32x2 -> bf16x2 (lo->low16, hi->high16), RNE
__device__ __forceinline__ unsigned cvt_pk_bf16(float lo, float hi) {
    unsigned r;
    asm("v_cvt_pk_bf16_f32 %0, %1, %2" : "=v"(r) : "v"(lo), "v"(hi));
    return r;
}

// Block-wide barrier that does NOT drain vmcnt: LDS writes are made visible
// (lgkmcnt(0)) but global prefetch loads stay in flight across the barrier.
__device__ __forceinline__ void block_sync_lds() {
    __builtin_amdgcn_sched_barrier(0);
    asm volatile("s_waitcnt lgkmcnt(0)" ::: "memory");
    __builtin_amdgcn_s_barrier();
    __builtin_amdgcn_sched_barrier(0);
}

// ---------------------------------------------------------------------------
// Pre-pass: act_table f32 -> bf16 (row-major, same layout). 8 floats/thread.
// (bf16 table halves gather bytes + L2 footprint; r11 proved deleting it
// costs +22 us on the LSTM.)
// ---------------------------------------------------------------------------
__global__ __launch_bounds__(256)
void cvt_table(const float* __restrict__ src, unsigned* __restrict__ dst)
{
    const int i = blockIdx.x * 256 + threadIdx.x;          // unit = 8 floats
    if (i < (NACT * EE) / 8) {
        const float4* s = reinterpret_cast<const float4*>(src) + (size_t)i * 2;
        float4 a = s[0], b = s[1];
        uint4 o;
        o.x = cvt_pk_bf16(a.x, a.y);
        o.y = cvt_pk_bf16(a.z, a.w);
        o.z = cvt_pk_bf16(b.x, b.y);
        o.w = cvt_pk_bf16(b.z, b.w);
        reinterpret_cast<uint4*>(dst)[i] = o;
    }
}

// ---------------------------------------------------------------------------
// MFMA LSTM (r10 structure: dual-chain + exp2 fold, 95.5 us) + FUSED GCN
// GATHER. The GCN neighborhood sum has no m_act dependency, and this kernel
// runs at 5% HBM / 52% VALU -- so the 33-row user_table gather for this
// block's 32 (b,m) pairs is interleaved one row-slice per step (steps 0..32),
// double-buffered, filling memory-latency bubbles. Gather loads are issued
// BEFORE the x-prefetch each step so counted vmcnt waits never drain the x
// pipeline. FP sum order identical to the r10 post_kernel (member, then
// neighbors serially). agg written to ws for post2.
// ---------------------------------------------------------------------------
__global__ __launch_bounds__(256, 2)
void lstm_mfma(const int* __restrict__ act_seqs, const unsigned short* __restrict__ act_bf,
               const int* __restrict__ members, const int* __restrict__ neighbors,
               const float* __restrict__ user_table,
               const float* __restrict__ W_ih, const float* __restrict__ W_hh,
               const float* __restrict__ b_ih, const float* __restrict__ b_hh,
               float* __restrict__ m_act, float* __restrict__ agg_out)
{
    __shared__ __align__(16) short sH[4][1024];   // tile = buf*2 + chain; [16][64] bf16 swizzled
    __shared__ int sIdx[32 * LL];                 // act_seqs for this block
    __shared__ int sNbr[32 * 33];                 // gather row ids: member + 32 nbrs per pair

    const int t    = threadIdx.x;
    const int blk  = blockIdx.x;
    const int lane = t & 63;
    const int w    = t >> 6;        // wave id = e-block (0..3)
    const int lr   = lane & 15;     // A row (seq) / B,D col selector
    const int lb   = lane >> 4;     // k-block / D row-block selector

    // --- this block's indices (contiguous 1600 ints, coalesced)
    for (int i = t; i < 32 * LL; i += 256) sIdx[i] = act_seqs[blk * (32 * LL) + i];
    // --- gather row ids: pair p (= global b*16+m = blk*32+p), j=0 member, 1..32 nbrs
    for (int i = t; i < 32 * 33; i += 256) {
        const int p = i / 33, j = i - p * 33;
        const int base = blk * 32 + p;
        sNbr[i] = (j == 0) ? members[base] : neighbors[base * KK + j - 1];
    }

    // per-gate exp2 fold scales (i,f,o: -log2e; g: +2*log2e)
    const float L2E = 1.44269504088896f;
    float gscale[4];
    gscale[0] = -L2E; gscale[1] = -L2E; gscale[2] = 2.0f * L2E; gscale[3] = -L2E;

    // --- weights -> register B-frags, SCALED. gates = in @ W^T => B[k][j]=W[j][k].
    short8 Bf[2][4][2];   // [mat(ih,hh)][gate][ks]
    #pragma unroll
    for (int mat = 0; mat < 2; ++mat) {
        const float* W = mat ? W_hh : W_ih;
        #pragma unroll
        for (int g = 0; g < 4; ++g) {
            const int j = g * 64 + w * 16 + lr;
            const float sc = gscale[g];
            #pragma unroll
            for (int ks = 0; ks < 2; ++ks) {
                const float4* p = reinterpret_cast<const float4*>(&W[(size_t)j * 64 + ks * 32 + lb * 8]);
                float4 v0 = p[0], v1 = p[1];
                uint4 o;
                o.x = cvt_pk_bf16(sc * v0.x, sc * v0.y);
                o.y = cvt_pk_bf16(sc * v0.z, sc * v0.w);
                o.z = cvt_pk_bf16(sc * v1.x, sc * v1.y);
                o.w = cvt_pk_bf16(sc * v1.z, sc * v1.w);
                Bf[mat][g][ks] = __builtin_bit_cast(short8, o);
            }
        }
    }
    float bias[4];
    #pragma unroll
    for (int g = 0; g < 4; ++g) {
        const int j = g * 64 + w * 16 + lr;
        bias[g] = gscale[g] * (b_ih[j] + b_hh[j]);
    }

    float hA[4], cA[4], hB[4], cB[4];
    #pragma unroll
    for (int r = 0; r < 4; ++r) { hA[r] = 0.0f; cA[r] = 0.0f; hB[r] = 0.0f; cB[r] = 0.0f; }

    // zero buf0 (tiles 0,1 = 4096 B = 256 x uint4)
    reinterpret_cast<uint4*>(sH)[t] = make_uint4(0u, 0u, 0u, 0u);
    __syncthreads();   // sIdx + sNbr + sH buf0 visible (once, outside loop)

    // --- gather lane mapping: pair p = t>>3 owns row blk*32+p; chunk ec = t&7
    const int gpair = t >> 3;
    const int gec   = t & 7;
    const float* gut = user_table + (size_t)gec * 8;
    float gacc[8];
    #pragma unroll
    for (int q = 0; q < 8; ++q) gacc[q] = 0.0f;
    // pre-issue gather row 0 (BEFORE x pre-loads: older in vmcnt FIFO)
    float4 gld0, gld1;
    {
        const int gi = sNbr[gpair * 33 + 0];
        const float4* gp = reinterpret_cast<const float4*>(gut + (size_t)gi * EE);
        gld0 = gp[0]; gld1 = gp[1];
    }

    // --- x gather: lane's frag = bytes [id*128 + lb*16] and +64.
    const char* tbl8 = reinterpret_cast<const char*>(act_bf) + lb * 16;
    const int ibA = lr * LL;           // chain A: seq lr
    const int ibB = (16 + lr) * LL;    // chain B: seq 16+lr

    int idA = sIdx[ibA + 0], idB = sIdx[ibB + 0];
    short8 axA0 = *reinterpret_cast<const short8*>(tbl8 + (size_t)idA * 128);
    short8 axA1 = *reinterpret_cast<const short8*>(tbl8 + (size_t)idA * 128 + 64);
    short8 axB0 = *reinterpret_cast<const short8*>(tbl8 + (size_t)idB * 128);
    short8 axB1 = *reinterpret_cast<const short8*>(tbl8 + (size_t)idB * 128 + 64);
    idA = sIdx[ibA + 1]; idB = sIdx[ibB + 1];

    // LDS byte offsets (loop-invariant)
    const int offA0 = lr * 128 + ((lb ^ (lr & 7)) << 4);
    const int offA1 = lr * 128 + (((lb + 4) ^ (lr & 7)) << 4);
    int hw_off[4];
    #pragma unroll
    for (int r = 0; r < 4; ++r) {
        const int s = lb * 4 + r, e = w * 16 + lr;
        hw_off[r] = s * 128 + ((((e >> 3) ^ (s & 7)) << 4)) + (e & 7) * 2;
    }
    char* const sHb = reinterpret_cast<char*>(sH);

    #pragma unroll 2
    for (int step = 0; step < LL; ++step) {
        const int cb  = (step & 1) << 12;   // current buf base: 0 or 4096
        const int nb_ = cb ^ 4096;          // next buf base

        // 0. fused GCN gather: accumulate row `step` (loaded last step),
        //    then issue row step+1. Issued BEFORE x prefetch -> older in
        //    vmcnt FIFO -> waits here never drain the x pipeline.
        if (step < 33) {
            gacc[0] += gld0.x; gacc[1] += gld0.y; gacc[2] += gld0.z; gacc[3] += gld0.w;
            gacc[4] += gld1.x; gacc[5] += gld1.y; gacc[6] += gld1.z; gacc[7] += gld1.w;
            if (step < 32) {
                const int gi = sNbr[gpair * 33 + step + 1];
                const float4* gp = reinterpret_cast<const float4*>(gut + (size_t)gi * EE);
                gld0 = gp[0]; gld1 = gp[1];
            }
        }

        // 1. issue x prefetch for step+1 (stays in flight across the barrier)
        short8 nxA0 = *reinterpret_cast<const short8*>(tbl8 + (size_t)idA * 128);
        short8 nxA1 = *reinterpret_cast<const short8*>(tbl8 + (size_t)idA * 128 + 64);
        short8 nxB0 = *reinterpret_cast<const short8*>(tbl8 + (size_t)idB * 128);
        short8 nxB1 = *reinterpret_cast<const short8*>(tbl8 + (size_t)idB * 128 + 64);
        {
            const int s2 = (step + 2 < LL) ? (step + 2) : (LL - 1);
            idA = sIdx[ibA + s2]; idB = sIdx[ibB + s2];
        }

        // 2. read h A-frags for both chains (swizzled, conflict-free)
        short8 ahA0 = *reinterpret_cast<const short8*>(sHb + cb + offA0);
        short8 ahA1 = *reinterpret_cast<const short8*>(sHb + cb + offA1);
        short8 ahB0 = *reinterpret_cast<const short8*>(sHb + cb + 2048 + offA0);
        short8 ahB1 = *reinterpret_cast<const short8*>(sHb + cb + 2048 + offA1);

        // 3. acc = scaled_bias + x @ sWih^T + h @ sWhh^T  (2 independent chains)
        v4f accA[4], accB[4];
        #pragma unroll
        for (int g = 0; g < 4; ++g) {
            v4f a; a[0] = bias[g]; a[1] = bias[g]; a[2] = bias[g]; a[3] = bias[g];
            accA[g] = a; accB[g] = a;
        }
        #pragma unroll
        for (int g = 0; g < 4; ++g) {
            accA[g] = __builtin_amdgcn_mfma_f32_16x16x32_bf16(axA0, Bf[0][g][0], accA[g], 0, 0, 0);
            accA[g] = __builtin_amdgcn_mfma_f32_16x16x32_bf16(axA1, Bf[0][g][1], accA[g], 0, 0, 0);
            accA[g] = __builtin_amdgcn_mfma_f32_16x16x32_bf16(ahA0, Bf[1][g][0], accA[g], 0, 0, 0);
            accA[g] = __builtin_amdgcn_mfma_f32_16x16x32_bf16(ahA1, Bf[1][g][1], accA[g], 0, 0, 0);
        }
        #pragma unroll
        for (int g = 0; g < 4; ++g) {
            accB[g] = __builtin_amdgcn_mfma_f32_16x16x32_bf16(axB0, Bf[0][g][0], accB[g], 0, 0, 0);
            accB[g] = __builtin_amdgcn_mfma_f32_16x16x32_bf16(axB1, Bf[0][g][1], accB[g], 0, 0, 0);
            accB[g] = __builtin_amdgcn_mfma_f32_16x16x32_bf16(ahB0, Bf[1][g][0], accB[g], 0, 0, 0);
            accB[g] = __builtin_amdgcn_mfma_f32_16x16x32_bf16(ahB1, Bf[1][g][1], accB[g], 0, 0, 0);
        }

        // 4. gate nonlinearities (exp2 args straight from MFMA) + h writes
        {
            char* SH = sHb + nb_;
            #pragma unroll
            for (int r = 0; r < 4; ++r) {
                const float si = rcpf(1.0f + exp2_fast(accA[0][r]));
                const float sf = rcpf(1.0f + exp2_fast(accA[1][r]));
                const float tg = fmaf(-2.0f, rcpf(1.0f + exp2_fast(accA[2][r])), 1.0f);
                const float so = rcpf(1.0f + exp2_fast(accA[3][r]));
                const float cc = fmaf(sf, cA[r], si * tg);
                cA[r] = cc;
                hA[r] = so * fmaf(-2.0f, rcpf(1.0f + exp2_fast(cc * (2.0f * L2E))), 1.0f);
            }
            const unsigned a01 = cvt_pk_bf16(hA[0], hA[1]);
            const unsigned a23 = cvt_pk_bf16(hA[2], hA[3]);
            *reinterpret_cast<short*>(SH + hw_off[0]) = (short)(a01 & 0xFFFF);
            *reinterpret_cast<short*>(SH + hw_off[1]) = (short)(a01 >> 16);
            *reinterpret_cast<short*>(SH + hw_off[2]) = (short)(a23 & 0xFFFF);
            *reinterpret_cast<short*>(SH + hw_off[3]) = (short)(a23 >> 16);
            SH += 2048;
            #pragma unroll
            for (int r = 0; r < 4; ++r) {
                const float si = rcpf(1.0f + exp2_fast(accB[0][r]));
                const float sf = rcpf(1.0f + exp2_fast(accB[1][r]));
                const float tg = fmaf(-2.0f, rcpf(1.0f + exp2_fast(accB[2][r])), 1.0f);
                const float so = rcpf(1.0f + exp2_fast(accB[3][r]));
                const float cc = fmaf(sf, cB[r], si * tg);
                cB[r] = cc;
                hB[r] = so * fmaf(-2.0f, rcpf(1.0f + exp2_fast(cc * (2.0f * L2E))), 1.0f);
            }
            const unsigned b01 = cvt_pk_bf16(hB[0], hB[1]);
            const unsigned b23 = cvt_pk_bf16(hB[2], hB[3]);
            *reinterpret_cast<short*>(SH + hw_off[0]) = (short)(b01 & 0xFFFF);
            *reinterpret_cast<short*>(SH + hw_off[1]) = (short)(b01 >> 16);
            *reinterpret_cast<short*>(SH + hw_off[2]) = (short)(b23 & 0xFFFF);
            *reinterpret_cast<short*>(SH + hw_off[3]) = (short)(b23 >> 16);
        }

        // 5. LDS-only barrier (x + gather loads stay in flight)
        block_sync_lds();

        // 6. roll prefetch regs (unroll-2 lets the allocator rename these)
        axA0 = nxA0; axA1 = nxA1; axB0 = nxB0; axB1 = nxB1;
    }

    // --- write final h -> m_act [16384][64] f32 (chain A then B)
    #pragma unroll
    for (int r = 0; r < 4; ++r) {
        const int s = lb * 4 + r;
        m_act[((size_t)(blk * 32 + s)) * EE + w * 16 + lr]      = hA[r];
        m_act[((size_t)(blk * 32 + 16 + s)) * EE + w * 16 + lr] = hB[r];
    }
    // --- write GCN agg (sum/33) -> agg_out [16384][64] f32
    {
        const float sc = 1.0f / 33.0f;
        float4 o0, o1;
        o0.x = gacc[0] * sc; o0.y = gacc[1] * sc; o0.z = gacc[2] * sc; o0.w = gacc[3] * sc;
        o1.x = gacc[4] * sc; o1.y = gacc[5] * sc; o1.z = gacc[6] * sc; o1.w = gacc[7] * sc;
        float* orow = &agg_out[((size_t)(blk * 32 + gpair)) * EE + gec * 8];
        *reinterpret_cast<float4*>(orow)     = o0;
        *reinterpret_cast<float4*>(orow + 4) = o1;
    }
}

// ---------------------------------------------------------------------------
// Kernel B (post2): GCN linear/relu (agg precomputed by lstm_mfma) + fuse +
// PNA reduce + MLPs + predict. One block per batch element b.
// ---------------------------------------------------------------------------
__global__ __launch_bounds__(256)
void post2_kernel(const int* __restrict__ act_inputs,
                  const float* __restrict__ act_table,
                  const float* __restrict__ gcn_W, const float* __restrict__ gcn_b,
                  const float* __restrict__ pna_W1, const float* __restrict__ pna_b1,
                  const float* __restrict__ pna_W2, const float* __restrict__ pna_b2,
                  const float* __restrict__ pna_W3, const float* __restrict__ pna_b3,
                  const float* __restrict__ pred_W1, const float* __restrict__ pred_b1,
                  const float* __restrict__ pred_W2, const float* __restrict__ pred_b2,
                  const float* __restrict__ m_act, const float* __restrict__ agg,
                  float* __restrict__ out)
{
    __shared__ float sWg[64][64];    // gcn_W transposed [k][e]
    __shared__ float sAgg[16][64];
    __shared__ float sFus[16][64];
    __shared__ float sActe[64];
    __shared__ float sFeats[256];
    __shared__ float sPart[4][64];
    __shared__ float sH1[64];
    __shared__ float sH2[64];
    __shared__ float sGrp[64];
    __shared__ float sHH[8];

    const int t  = threadIdx.x;
    const int b  = blockIdx.x;
    const int e  = t & 63;
    const int mq = t >> 6;   // 0..3 (wave id)

    {
        const int kq = (t & 15) * 4;
        const int er = t >> 4;   // 0..15
        #pragma unroll
        for (int rep = 0; rep < 4; ++rep) {
            int row = rep * 16 + er;
            float4 v = *reinterpret_cast<const float4*>(&gcn_W[row * 64 + kq]);
            sWg[kq + 0][row] = v.x;
            sWg[kq + 1][row] = v.y;
            sWg[kq + 2][row] = v.z;
            sWg[kq + 3][row] = v.w;
        }
    }
    if (t < 64) sActe[t] = act_table[(size_t)act_inputs[b] * EE + t];

    // agg precomputed (fused into lstm_mfma)
    #pragma unroll
    for (int mb = 0; mb < 4; ++mb) {
        int m = mb * 4 + mq;
        sAgg[m][e] = agg[((size_t)(b * MM + m)) * EE + e];
    }
    __syncthreads();

    for (int mb = 0; mb < 4; ++mb) {
        int m = mb * 4 + mq;
        float a = gcn_b[e];
        #pragma unroll
        for (int k = 0; k < 64; ++k) a = fmaf(sAgg[m][k], sWg[k][e], a);
        a = fmaxf(a, 0.0f);
        sFus[m][e] = m_act[((size_t)(b * MM + m)) * EE + e] + a;
    }
    __syncthreads();

    if (t < 64) {
        float mn = 0.0f, mx = -INFINITY;
        #pragma unroll
        for (int m = 0; m < MM; ++m) { float v = sFus[m][t]; mn += v; mx = fmaxf(mx, v); }
        mn *= (1.0f / 16.0f);
        sFeats[t] = mn; sFeats[64 + t] = mx; sFeats[128 + t] = mn; sFeats[192 + t] = mx;
    }
    __syncthreads();

    {
        float p = 0.0f;
        #pragma unroll 8
        for (int kk = 0; kk < 64; ++kk) {
            int k = mq * 64 + kk;
            p = fmaf(sFeats[k], pna_W1[(size_t)k * 64 + e], p);
        }
        sPart[mq][e] = p;
    }
    __syncthreads();
    if (t < 64) sH1[t] = fmaxf(pna_b1[t] + sPart[0][t] + sPart[1][t] + sPart[2][t] + sPart[3][t], 0.0f);
    __syncthreads();

    {
        float p = 0.0f;
        #pragma unroll
        for (int kk = 0; kk < 16; ++kk) {
            int k = mq * 16 + kk;
            p = fmaf(sH1[k], pna_W2[(size_t)k * 64 + e], p);
        }
        sPart[mq][e] = p;
    }
    __syncthreads();
    if (t < 64) sH2[t] = fmaxf(pna_b2[t] + sPart[0][t] + sPart[1][t] + sPart[2][t] + sPart[3][t], 0.0f);
    __syncthreads();

    {
        float p = 0.0f;
        #pragma unroll
        for (int kk = 0; kk < 16; ++kk) {
            int k = mq * 16 + kk;
            p = fmaf(sH2[k], pna_W3[(size_t)k * 64 + e], p);
        }
        sPart[mq][e] = p;
    }
    __syncthreads();
    if (t < 64) sGrp[t] = pna_b3[t] + sPart[0][t] + sPart[1][t] + sPart[2][t] + sPart[3][t];
    __syncthreads();

    if (t < 8) {
        float a = pred_b1[t];
        for (int k = 0; k < 192; ++k) {
            float cv = (k < 64) ? sGrp[k] * sActe[k]
                                : ((k < 128) ? sGrp[k - 64] : sActe[k - 128]);
            a = fmaf(cv, pred_W1[k * 8 + t], a);
        }
        sHH[t] = fmaxf(a, 0.0f);
    }
    __syncthreads();
    if (t == 0) {
        float y = pred_b2[0];
        #pragma unroll
        for (int j = 0; j < 8; ++j) y = fmaf(sHH[j], pred_W2[j], y);
        out[b] = 1.0f / (1.0f + expf(-y));
    }
}

extern "C" void kernel_launch(void* const* d_in, const int* in_sizes, int n_in,
                              void* d_out, int out_size, void* d_ws, size_t ws_size,
                              hipStream_t stream) {
    const int*   members    = (const int*)d_in[0];
    const int*   neighbors  = (const int*)d_in[1];
    const int*   act_inputs = (const int*)d_in[2];
    const int*   act_seqs   = (const int*)d_in[3];
    const float* act_table  = (const float*)d_in[4];
    const float* user_table = (const float*)d_in[5];
    const float* W_ih       = (const float*)d_in[6];
    const float* W_hh       = (const float*)d_in[7];
    const float* b_ih       = (const float*)d_in[8];
    const float* b_hh       = (const float*)d_in[9];
    const float* gcn_W      = (const float*)d_in[10];
    const float* gcn_b      = (const float*)d_in[11];
    const float* pna_W1     = (const float*)d_in[12];
    const float* pna_b1     = (const float*)d_in[13];
    const float* pna_W2     = (const float*)d_in[14];
    const float* pna_b2     = (const float*)d_in[15];
    const float* pna_W3     = (const float*)d_in[16];
    const float* pna_b3     = (const float*)d_in[17];
    const float* pred_W1    = (const float*)d_in[18];
    const float* pred_b1    = (const float*)d_in[19];
    const float* pred_W2    = (const float*)d_in[20];
    const float* pred_b2    = (const float*)d_in[21];

    char* ws = (char*)d_ws;
    float*          m_act  = (float*)ws;                                   // 4 MB
    unsigned short* act_bf = (unsigned short*)(ws + 4194304);              // 12.8 MB
    float*          agg    = (float*)(ws + 4194304 + (size_t)NACT * EE * 2); // 4 MB

    cvt_table<<<dim3((NACT * EE / 8 + 255) / 256), dim3(256), 0, stream>>>(
        act_table, (unsigned*)act_bf);

    lstm_mfma<<<dim3(512), dim3(256), 0, stream>>>(
        act_seqs, act_bf, members, neighbors, user_table,
        W_ih, W_hh, b_ih, b_hh, m_act, agg);

    post2_kernel<<<dim3(BB), dim3(256), 0, stream>>>(
        act_inputs, act_table,
        gcn_W, gcn_b, pna_W1, pna_b1, pna_W2, pna_b2, pna_W3, pna_b3,
        pred_W1, pred_b1, pred_W2, pred_b2, m_act, agg, (float*)d_out);
}

// Round 14
// 124.399 us; speedup vs baseline: 1.4356x; 1.1486x over previous
//
#include <hip/hip_runtime.h>
#include <hip/hip_bf16.h>
#include <math.h>

// Problem constants (match reference)
#define BB   1024
#define MM   16
#define KK   32
#define LL   50
#define EE   64
#define NACT 100000

typedef __attribute__((ext_vector_type(8))) short short8;
typedef float v4f __attribute__((ext_vector_type(4)));

__device__ __forceinline__ float rcpf(float x) { return __builtin_amdgcn_rcpf(x); }
// native 2^x (v_exp_f32 IS exp2)
__device__ __forceinline__ float exp2_fast(float x) {
    float r;
    asm("v_exp_f32 %0, %1" : "=v"(r) : "v"(x));
    return r;
}

// packed f32x2 -> bf16x2 (lo->low16, hi->high16), RNE
__device__ __forceinline__ unsigned cvt_pk_bf16(float lo, float hi) {
    unsigned r;
    asm("v_cvt_pk_bf16_f32 %0, %1, %2" : "=v"(r) : "v"(lo), "v"(hi));
    return r;
}

// Block-wide barrier that does NOT drain vmcnt: LDS writes are made visible
// (lgkmcnt(0)) but global prefetch loads stay in flight across the barrier.
__device__ __forceinline__ void block_sync_lds() {
    __builtin_amdgcn_sched_barrier(0);
    asm volatile("s_waitcnt lgkmcnt(0)" ::: "memory");
    __builtin_amdgcn_s_barrier();
    __builtin_amdgcn_sched_barrier(0);
}

// ---------------------------------------------------------------------------
// Pre-pass: act_table f32 -> bf16 (row-major, same layout). 8 floats/thread.
// (bf16 table halves gather bytes + L2 footprint; r11 proved deleting it
// costs +22 us on the LSTM.)
// ---------------------------------------------------------------------------
__global__ __launch_bounds__(256)
void cvt_table(const float* __restrict__ src, unsigned* __restrict__ dst)
{
    const int i = blockIdx.x * 256 + threadIdx.x;          // unit = 8 floats
    if (i < (NACT * EE) / 8) {
        const float4* s = reinterpret_cast<const float4*>(src) + (size_t)i * 2;
        float4 a = s[0], b = s[1];
        uint4 o;
        o.x = cvt_pk_bf16(a.x, a.y);
        o.y = cvt_pk_bf16(a.z, a.w);
        o.z = cvt_pk_bf16(b.x, b.y);
        o.w = cvt_pk_bf16(b.z, b.w);
        reinterpret_cast<uint4*>(dst)[i] = o;
    }
}

// ---------------------------------------------------------------------------
// FULLY-FUSED kernel: r13 LSTM loop (dual-chain + exp2 fold + interleaved
// GCN gather) + complete post pipeline as an epilogue. Each block owns 32
// (b,m) pairs = batches b0=2*blk and b0+1, so after the step loop it holds
// final h (registers) and GCN agg (registers) for both batches and can run
// gcn-linear -> fuse -> PNA -> MLPs -> predict entirely in-block, writing
// out[2*blk+q] directly. Deletes post2 kernel + 8 MB m_act/agg round-trip.
// Hot loop is byte-identical to r13 (112.5 us).
// LDS ~57 KB -> still 2 blocks/CU (114 < 160 KB).
// ---------------------------------------------------------------------------
__global__ __launch_bounds__(256, 2)
void lstm_fused(const int* __restrict__ act_seqs, const unsigned short* __restrict__ act_bf,
                const int* __restrict__ members, const int* __restrict__ neighbors,
                const float* __restrict__ user_table,
                const float* __restrict__ W_ih, const float* __restrict__ W_hh,
                const float* __restrict__ b_ih, const float* __restrict__ b_hh,
                const int* __restrict__ act_inputs, const float* __restrict__ act_table,
                const float* __restrict__ gcn_W, const float* __restrict__ gcn_b,
                const float* __restrict__ pna_W1, const float* __restrict__ pna_b1,
                const float* __restrict__ pna_W2, const float* __restrict__ pna_b2,
                const float* __restrict__ pna_W3, const float* __restrict__ pna_b3,
                const float* __restrict__ pred_W1, const float* __restrict__ pred_b1,
                const float* __restrict__ pred_W2, const float* __restrict__ pred_b2,
                float* __restrict__ out)
{
    // --- loop-phase LDS
    __shared__ __align__(16) short sH[4][1024];   // h dbuf (bf16 swizzled), 8 KB
    __shared__ int sIdx[32 * LL];                 // 6.4 KB
    __shared__ int sNbr[32 * 33];                 // 4.2 KB
    // --- epilogue LDS (no aliasing; total ~57 KB)
    __shared__ float sFus[32][64];                // h, then fus (8 KB)
    __shared__ float sAgg[32][64];                // 8 KB
    __shared__ float sWg[64][66];                 // gcn_W row-major, padded (16.9 KB)
    __shared__ float sF[2][256];                  // PNA feats
    __shared__ float sP[2][2][64];                // pna1 partials
    __shared__ float sH1[2][64];
    __shared__ float sH2[2][64];
    __shared__ float sGrp[2][64];
    __shared__ float sActe[2][64];
    __shared__ float sHH[2][8];

    const int t    = threadIdx.x;
    const int blk  = blockIdx.x;
    const int lane = t & 63;
    const int w    = t >> 6;        // wave id = e-block (0..3)
    const int lr   = lane & 15;     // A row (seq) / B,D col selector
    const int lb   = lane >> 4;     // k-block / D row-block selector

    // --- this block's indices (contiguous 1600 ints, coalesced)
    for (int i = t; i < 32 * LL; i += 256) sIdx[i] = act_seqs[blk * (32 * LL) + i];
    // --- gather row ids: pair p (= global b*16+m = blk*32+p), j=0 member, 1..32 nbrs
    for (int i = t; i < 32 * 33; i += 256) {
        const int p = i / 33, j = i - p * 33;
        const int base = blk * 32 + p;
        sNbr[i] = (j == 0) ? members[base] : neighbors[base * KK + j - 1];
    }

    // per-gate exp2 fold scales (i,f,o: -log2e; g: +2*log2e)
    const float L2E = 1.44269504088896f;
    float gscale[4];
    gscale[0] = -L2E; gscale[1] = -L2E; gscale[2] = 2.0f * L2E; gscale[3] = -L2E;

    // --- weights -> register B-frags, SCALED. gates = in @ W^T => B[k][j]=W[j][k].
    short8 Bf[2][4][2];   // [mat(ih,hh)][gate][ks]
    #pragma unroll
    for (int mat = 0; mat < 2; ++mat) {
        const float* W = mat ? W_hh : W_ih;
        #pragma unroll
        for (int g = 0; g < 4; ++g) {
            const int j = g * 64 + w * 16 + lr;
            const float sc = gscale[g];
            #pragma unroll
            for (int ks = 0; ks < 2; ++ks) {
                const float4* p = reinterpret_cast<const float4*>(&W[(size_t)j * 64 + ks * 32 + lb * 8]);
                float4 v0 = p[0], v1 = p[1];
                uint4 o;
                o.x = cvt_pk_bf16(sc * v0.x, sc * v0.y);
                o.y = cvt_pk_bf16(sc * v0.z, sc * v0.w);
                o.z = cvt_pk_bf16(sc * v1.x, sc * v1.y);
                o.w = cvt_pk_bf16(sc * v1.z, sc * v1.w);
                Bf[mat][g][ks] = __builtin_bit_cast(short8, o);
            }
        }
    }
    float bias[4];
    #pragma unroll
    for (int g = 0; g < 4; ++g) {
        const int j = g * 64 + w * 16 + lr;
        bias[g] = gscale[g] * (b_ih[j] + b_hh[j]);
    }

    float hA[4], cA[4], hB[4], cB[4];
    #pragma unroll
    for (int r = 0; r < 4; ++r) { hA[r] = 0.0f; cA[r] = 0.0f; hB[r] = 0.0f; cB[r] = 0.0f; }

    // zero buf0 (tiles 0,1 = 4096 B = 256 x uint4)
    reinterpret_cast<uint4*>(sH)[t] = make_uint4(0u, 0u, 0u, 0u);
    __syncthreads();   // sIdx + sNbr + sH buf0 visible (once, outside loop)

    // --- gather lane mapping: pair p = t>>3 owns row blk*32+p; chunk ec = t&7
    const int gpair = t >> 3;
    const int gec   = t & 7;
    const float* gut = user_table + (size_t)gec * 8;
    float gacc[8];
    #pragma unroll
    for (int q = 0; q < 8; ++q) gacc[q] = 0.0f;
    // pre-issue gather row 0 (BEFORE x pre-loads: older in vmcnt FIFO)
    float4 gld0, gld1;
    {
        const int gi = sNbr[gpair * 33 + 0];
        const float4* gp = reinterpret_cast<const float4*>(gut + (size_t)gi * EE);
        gld0 = gp[0]; gld1 = gp[1];
    }

    // --- x gather: lane's frag = bytes [id*128 + lb*16] and +64.
    const char* tbl8 = reinterpret_cast<const char*>(act_bf) + lb * 16;
    const int ibA = lr * LL;           // chain A: seq lr
    const int ibB = (16 + lr) * LL;    // chain B: seq 16+lr

    int idA = sIdx[ibA + 0], idB = sIdx[ibB + 0];
    short8 axA0 = *reinterpret_cast<const short8*>(tbl8 + (size_t)idA * 128);
    short8 axA1 = *reinterpret_cast<const short8*>(tbl8 + (size_t)idA * 128 + 64);
    short8 axB0 = *reinterpret_cast<const short8*>(tbl8 + (size_t)idB * 128);
    short8 axB1 = *reinterpret_cast<const short8*>(tbl8 + (size_t)idB * 128 + 64);
    idA = sIdx[ibA + 1]; idB = sIdx[ibB + 1];

    // LDS byte offsets (loop-invariant)
    const int offA0 = lr * 128 + ((lb ^ (lr & 7)) << 4);
    const int offA1 = lr * 128 + (((lb + 4) ^ (lr & 7)) << 4);
    int hw_off[4];
    #pragma unroll
    for (int r = 0; r < 4; ++r) {
        const int s = lb * 4 + r, e = w * 16 + lr;
        hw_off[r] = s * 128 + ((((e >> 3) ^ (s & 7)) << 4)) + (e & 7) * 2;
    }
    char* const sHb = reinterpret_cast<char*>(sH);

    #pragma unroll 2
    for (int step = 0; step < LL; ++step) {
        const int cb  = (step & 1) << 12;   // current buf base: 0 or 4096
        const int nb_ = cb ^ 4096;          // next buf base

        // 0. fused GCN gather: accumulate row `step` (loaded last step),
        //    then issue row step+1 (BEFORE x prefetch -> older in vmcnt FIFO).
        if (step < 33) {
            gacc[0] += gld0.x; gacc[1] += gld0.y; gacc[2] += gld0.z; gacc[3] += gld0.w;
            gacc[4] += gld1.x; gacc[5] += gld1.y; gacc[6] += gld1.z; gacc[7] += gld1.w;
            if (step < 32) {
                const int gi = sNbr[gpair * 33 + step + 1];
                const float4* gp = reinterpret_cast<const float4*>(gut + (size_t)gi * EE);
                gld0 = gp[0]; gld1 = gp[1];
            }
        }

        // 1. issue x prefetch for step+1 (stays in flight across the barrier)
        short8 nxA0 = *reinterpret_cast<const short8*>(tbl8 + (size_t)idA * 128);
        short8 nxA1 = *reinterpret_cast<const short8*>(tbl8 + (size_t)idA * 128 + 64);
        short8 nxB0 = *reinterpret_cast<const short8*>(tbl8 + (size_t)idB * 128);
        short8 nxB1 = *reinterpret_cast<const short8*>(tbl8 + (size_t)idB * 128 + 64);
        {
            const int s2 = (step + 2 < LL) ? (step + 2) : (LL - 1);
            idA = sIdx[ibA + s2]; idB = sIdx[ibB + s2];
        }

        // 2. read h A-frags for both chains (swizzled, conflict-free)
        short8 ahA0 = *reinterpret_cast<const short8*>(sHb + cb + offA0);
        short8 ahA1 = *reinterpret_cast<const short8*>(sHb + cb + offA1);
        short8 ahB0 = *reinterpret_cast<const short8*>(sHb + cb + 2048 + offA0);
        short8 ahB1 = *reinterpret_cast<const short8*>(sHb + cb + 2048 + offA1);

        // 3. acc = scaled_bias + x @ sWih^T + h @ sWhh^T  (2 independent chains)
        v4f accA[4], accB[4];
        #pragma unroll
        for (int g = 0; g < 4; ++g) {
            v4f a; a[0] = bias[g]; a[1] = bias[g]; a[2] = bias[g]; a[3] = bias[g];
            accA[g] = a; accB[g] = a;
        }
        #pragma unroll
        for (int g = 0; g < 4; ++g) {
            accA[g] = __builtin_amdgcn_mfma_f32_16x16x32_bf16(axA0, Bf[0][g][0], accA[g], 0, 0, 0);
            accA[g] = __builtin_amdgcn_mfma_f32_16x16x32_bf16(axA1, Bf[0][g][1], accA[g], 0, 0, 0);
            accA[g] = __builtin_amdgcn_mfma_f32_16x16x32_bf16(ahA0, Bf[1][g][0], accA[g], 0, 0, 0);
            accA[g] = __builtin_amdgcn_mfma_f32_16x16x32_bf16(ahA1, Bf[1][g][1], accA[g], 0, 0, 0);
        }
        #pragma unroll
        for (int g = 0; g < 4; ++g) {
            accB[g] = __builtin_amdgcn_mfma_f32_16x16x32_bf16(axB0, Bf[0][g][0], accB[g], 0, 0, 0);
            accB[g] = __builtin_amdgcn_mfma_f32_16x16x32_bf16(axB1, Bf[0][g][1], accB[g], 0, 0, 0);
            accB[g] = __builtin_amdgcn_mfma_f32_16x16x32_bf16(ahB0, Bf[1][g][0], accB[g], 0, 0, 0);
            accB[g] = __builtin_amdgcn_mfma_f32_16x16x32_bf16(ahB1, Bf[1][g][1], accB[g], 0, 0, 0);
        }

        // 4. gate nonlinearities (exp2 args straight from MFMA) + h writes
        {
            char* SH = sHb + nb_;
            #pragma unroll
            for (int r = 0; r < 4; ++r) {
                const float si = rcpf(1.0f + exp2_fast(accA[0][r]));
                const float sf = rcpf(1.0f + exp2_fast(accA[1][r]));
                const float tg = fmaf(-2.0f, rcpf(1.0f + exp2_fast(accA[2][r])), 1.0f);
                const float so = rcpf(1.0f + exp2_fast(accA[3][r]));
                const float cc = fmaf(sf, cA[r], si * tg);
                cA[r] = cc;
                hA[r] = so * fmaf(-2.0f, rcpf(1.0f + exp2_fast(cc * (2.0f * L2E))), 1.0f);
            }
            const unsigned a01 = cvt_pk_bf16(hA[0], hA[1]);
            const unsigned a23 = cvt_pk_bf16(hA[2], hA[3]);
            *reinterpret_cast<short*>(SH + hw_off[0]) = (short)(a01 & 0xFFFF);
            *reinterpret_cast<short*>(SH + hw_off[1]) = (short)(a01 >> 16);
            *reinterpret_cast<short*>(SH + hw_off[2]) = (short)(a23 & 0xFFFF);
            *reinterpret_cast<short*>(SH + hw_off[3]) = (short)(a23 >> 16);
            SH += 2048;
            #pragma unroll
            for (int r = 0; r < 4; ++r) {
                const float si = rcpf(1.0f + exp2_fast(accB[0][r]));
                const float sf = rcpf(1.0f + exp2_fast(accB[1][r]));
                const float tg = fmaf(-2.0f, rcpf(1.0f + exp2_fast(accB[2][r])), 1.0f);
                const float so = rcpf(1.0f + exp2_fast(accB[3][r]));
                const float cc = fmaf(sf, cB[r], si * tg);
                cB[r] = cc;
                hB[r] = so * fmaf(-2.0f, rcpf(1.0f + exp2_fast(cc * (2.0f * L2E))), 1.0f);
            }
            const unsigned b01 = cvt_pk_bf16(hB[0], hB[1]);
            const unsigned b23 = cvt_pk_bf16(hB[2], hB[3]);
            *reinterpret_cast<short*>(SH + hw_off[0]) = (short)(b01 & 0xFFFF);
            *reinterpret_cast<short*>(SH + hw_off[1]) = (short)(b01 >> 16);
            *reinterpret_cast<short*>(SH + hw_off[2]) = (short)(b23 & 0xFFFF);
            *reinterpret_cast<short*>(SH + hw_off[3]) = (short)(b23 >> 16);
        }

        // 5. LDS-only barrier (x + gather loads stay in flight)
        block_sync_lds();

        // 6. roll prefetch regs (unroll-2 lets the allocator rename these)
        axA0 = nxA0; axA1 = nxA1; axB0 = nxB0; axB1 = nxB1;
    }

    // ======================= FUSED POST EPILOGUE =======================
    // batches q=0,1 -> global b = blk*2 + q; local pair p = q*16 + m.

    // 1. h -> sFus (f32); agg/33 -> sAgg; stage gcn_W row-major [e][k] padded;
    //    acte for both batches.
    #pragma unroll
    for (int r = 0; r < 4; ++r) {
        sFus[lb * 4 + r][w * 16 + lr]      = hA[r];
        sFus[16 + lb * 4 + r][w * 16 + lr] = hB[r];
    }
    {
        const float sc = 1.0f / 33.0f;
        float* ar = &sAgg[gpair][gec * 8];
        #pragma unroll
        for (int q = 0; q < 8; ++q) ar[q] = gacc[q] * sc;
    }
    {
        const int row = t >> 2, cq = (t & 3) * 16;   // coalesced: 4 thr/row
        #pragma unroll
        for (int i = 0; i < 4; ++i) {
            float4 v = *reinterpret_cast<const float4*>(&gcn_W[row * 64 + cq + i * 4]);
            sWg[row][cq + i * 4 + 0] = v.x;
            sWg[row][cq + i * 4 + 1] = v.y;
            sWg[row][cq + i * 4 + 2] = v.z;
            sWg[row][cq + i * 4 + 3] = v.w;
        }
    }
    if (t < 128) {
        const int q = t >> 6, e = t & 63;
        sActe[q][e] = act_table[(size_t)act_inputs[blk * 2 + q] * EE + e];
    }
    __syncthreads();

    // 2. m_gcn = relu(agg @ gcn_W^T + b); fus = h + m_gcn  (in place)
    {
        const int m = t >> 3, e0 = (t & 7) * 8;
        float acc[8];
        #pragma unroll
        for (int i = 0; i < 8; ++i) acc[i] = gcn_b[e0 + i];
        for (int k = 0; k < 64; ++k) {
            const float a = sAgg[m][k];
            #pragma unroll
            for (int i = 0; i < 8; ++i) acc[i] = fmaf(a, sWg[e0 + i][k], acc[i]);
        }
        #pragma unroll
        for (int i = 0; i < 8; ++i) sFus[m][e0 + i] += fmaxf(acc[i], 0.0f);
    }
    __syncthreads();

    // 3. PNA reduce over M (amp = 1 exactly)
    if (t < 128) {
        const int q = t >> 6, e = t & 63;
        float mn = 0.0f, mx = -INFINITY;
        #pragma unroll
        for (int m = 0; m < MM; ++m) { float v = sFus[q * 16 + m][e]; mn += v; mx = fmaxf(mx, v); }
        mn *= (1.0f / 16.0f);
        sF[q][e] = mn; sF[q][64 + e] = mx; sF[q][128 + e] = mn; sF[q][192 + e] = mx;
    }
    __syncthreads();

    // 4. h1 = relu(feats @ pna_W1 + b1): 256->64, k split 2x128 over 256 thr
    {
        const int q = t >> 7, kh = (t >> 6) & 1, j = t & 63;
        float p = 0.0f;
        const float* Wp = pna_W1 + (size_t)(kh * 128) * 64 + j;
        const float* fp = &sF[q][kh * 128];
        #pragma unroll 8
        for (int k = 0; k < 128; ++k) p = fmaf(fp[k], Wp[(size_t)k * 64], p);
        sP[q][kh][j] = p;
    }
    __syncthreads();
    if (t < 128) {
        const int q = t >> 6, j = t & 63;
        sH1[q][j] = fmaxf(pna_b1[j] + sP[q][0][j] + sP[q][1][j], 0.0f);
    }
    __syncthreads();

    // 5. h2 = relu(h1 @ pna_W2 + b2)
    if (t < 128) {
        const int q = t >> 6, j = t & 63;
        float p = 0.0f;
        #pragma unroll 8
        for (int k = 0; k < 64; ++k) p = fmaf(sH1[q][k], pna_W2[(size_t)k * 64 + j], p);
        sH2[q][j] = fmaxf(pna_b2[j] + p, 0.0f);
    }
    __syncthreads();

    // 6. grp = h2 @ pna_W3 + b3
    if (t < 128) {
        const int q = t >> 6, j = t & 63;
        float p = 0.0f;
        #pragma unroll 8
        for (int k = 0; k < 64; ++k) p = fmaf(sH2[q][k], pna_W3[(size_t)k * 64 + j], p);
        sGrp[q][j] = pna_b3[j] + p;
    }
    __syncthreads();

    // 7. predict: cat = [grp*act_e, grp, act_e]; hh = relu(cat @ pred_W1 + b1)
    if (t < 16) {
        const int q = t >> 3, j = t & 7;
        float a = pred_b1[j];
        for (int k = 0; k < 192; ++k) {
            float cv = (k < 64) ? sGrp[q][k] * sActe[q][k]
                                : ((k < 128) ? sGrp[q][k - 64] : sActe[q][k - 128]);
            a = fmaf(cv, pred_W1[k * 8 + j], a);
        }
        sHH[q][j] = fmaxf(a, 0.0f);
    }
    __syncthreads();
    if (t < 2) {
        float y = pred_b2[0];
        #pragma unroll
        for (int jj = 0; jj < 8; ++jj) y = fmaf(sHH[t][jj], pred_W2[jj], y);
        out[blk * 2 + t] = 1.0f / (1.0f + expf(-y));
    }
}

extern "C" void kernel_launch(void* const* d_in, const int* in_sizes, int n_in,
                              void* d_out, int out_size, void* d_ws, size_t ws_size,
                              hipStream_t stream) {
    const int*   members    = (const int*)d_in[0];
    const int*   neighbors  = (const int*)d_in[1];
    const int*   act_inputs = (const int*)d_in[2];
    const int*   act_seqs   = (const int*)d_in[3];
    const float* act_table  = (const float*)d_in[4];
    const float* user_table = (const float*)d_in[5];
    const float* W_ih       = (const float*)d_in[6];
    const float* W_hh       = (const float*)d_in[7];
    const float* b_ih       = (const float*)d_in[8];
    const float* b_hh       = (const float*)d_in[9];
    const float* gcn_W      = (const float*)d_in[10];
    const float* gcn_b      = (const float*)d_in[11];
    const float* pna_W1     = (const float*)d_in[12];
    const float* pna_b1     = (const float*)d_in[13];
    const float* pna_W2     = (const float*)d_in[14];
    const float* pna_b2     = (const float*)d_in[15];
    const float* pna_W3     = (const float*)d_in[16];
    const float* pna_b3     = (const float*)d_in[17];
    const float* pred_W1    = (const float*)d_in[18];
    const float* pred_b1    = (const float*)d_in[19];
    const float* pred_W2    = (const float*)d_in[20];
    const float* pred_b2    = (const float*)d_in[21];

    unsigned short* act_bf = (unsigned short*)d_ws;   // 12.8 MB bf16 table

    cvt_table<<<dim3((NACT * EE / 8 + 255) / 256), dim3(256), 0, stream>>>(
        act_table, (unsigned*)act_bf);

    lstm_fused<<<dim3(512), dim3(256), 0, stream>>>(
        act_seqs, act_bf, members, neighbors, user_table,
        W_ih, W_hh, b_ih, b_hh,
        act_inputs, act_table,
        gcn_W, gcn_b, pna_W1, pna_b1, pna_W2, pna_b2, pna_W3, pna_b3,
        pred_W1, pred_b1, pred_W2, pred_b2, (float*)d_out);
}

// Round 15
// 106.016 us; speedup vs baseline: 1.6846x; 1.1734x over previous
//
#include <hip/hip_runtime.h>
#include <hip/hip_bf16.h>
#include <math.h>

// Problem constants (match reference)
#define BB   1024
#define MM   16
#define KK   32
#define LL   50
#define EE   64
#define NACT 100000

typedef __attribute__((ext_vector_type(8))) short short8;
typedef float v4f __attribute__((ext_vector_type(4)));

__device__ __forceinline__ float rcpf(float x) { return __builtin_amdgcn_rcpf(x); }
// native 2^x (v_exp_f32 IS exp2)
__device__ __forceinline__ float exp2_fast(float x) {
    float r;
    asm("v_exp_f32 %0, %1" : "=v"(r) : "v"(x));
    return r;
}

// packed f32x2 -> bf16x2 (lo->low16, hi->high16), RNE
__device__ __forceinline__ unsigned cvt_pk_bf16(float lo, float hi) {
    unsigned r;
    asm("v_cvt_pk_bf16_f32 %0, %1, %2" : "=v"(r) : "v"(lo), "v"(hi));
    return r;
}

// Block-wide barrier that does NOT drain vmcnt: LDS writes are made visible
// (lgkmcnt(0)) but global prefetch loads stay in flight across the barrier.
__device__ __forceinline__ void block_sync_lds() {
    __builtin_amdgcn_sched_barrier(0);
    asm volatile("s_waitcnt lgkmcnt(0)" ::: "memory");
    __builtin_amdgcn_s_barrier();
    __builtin_amdgcn_sched_barrier(0);
}

// ---------------------------------------------------------------------------
// Pre-pass: act_table f32 -> bf16 (row-major, same layout). 8 floats/thread.
// (bf16 table halves gather bytes + L2 footprint; r11 proved deleting it
// costs +22 us on the LSTM.)
// ---------------------------------------------------------------------------
__global__ __launch_bounds__(256)
void cvt_table(const float* __restrict__ src, unsigned* __restrict__ dst)
{
    const int i = blockIdx.x * 256 + threadIdx.x;          // unit = 8 floats
    if (i < (NACT * EE) / 8) {
        const float4* s = reinterpret_cast<const float4*>(src) + (size_t)i * 2;
        float4 a = s[0], b = s[1];
        uint4 o;
        o.x = cvt_pk_bf16(a.x, a.y);
        o.y = cvt_pk_bf16(a.z, a.w);
        o.z = cvt_pk_bf16(b.x, b.y);
        o.w = cvt_pk_bf16(b.z, b.w);
        reinterpret_cast<uint4*>(dst)[i] = o;
    }
}

// ---------------------------------------------------------------------------
// FULLY-FUSED kernel (r14 structure) with MFMA epilogue:
// r13 LSTM loop (dual-chain + exp2 fold + interleaved GCN gather) +
// post pipeline as epilogue. r14's epilogue GCN-linear did ~1100 scalar LDS
// reads/thread (4.37M bank conflicts, +27 us); now it's 4 MFMA per wave
// against register-resident gcn_W B-frags, with agg staged bf16 into the
// dead sH tiles using the same swizzle. MFMA D-layout == h register layout,
// so fus = h + relu(mfma+b) is register-local. MLP chain k-split for ILP.
// ---------------------------------------------------------------------------
__global__ __launch_bounds__(256, 2)
void lstm_fused(const int* __restrict__ act_seqs, const unsigned short* __restrict__ act_bf,
                const int* __restrict__ members, const int* __restrict__ neighbors,
                const float* __restrict__ user_table,
                const float* __restrict__ W_ih, const float* __restrict__ W_hh,
                const float* __restrict__ b_ih, const float* __restrict__ b_hh,
                const int* __restrict__ act_inputs, const float* __restrict__ act_table,
                const float* __restrict__ gcn_W, const float* __restrict__ gcn_b,
                const float* __restrict__ pna_W1, const float* __restrict__ pna_b1,
                const float* __restrict__ pna_W2, const float* __restrict__ pna_b2,
                const float* __restrict__ pna_W3, const float* __restrict__ pna_b3,
                const float* __restrict__ pred_W1, const float* __restrict__ pred_b1,
                const float* __restrict__ pred_W2, const float* __restrict__ pred_b2,
                float* __restrict__ out)
{
    // --- loop-phase LDS
    __shared__ __align__(16) short sH[4][1024];   // h dbuf (bf16 swizzled), 8 KB
    __shared__ int sIdx[32 * LL];                 // 6.4 KB
    __shared__ int sNbr[32 * 33];                 // 4.2 KB
    // --- epilogue LDS (~14 KB)
    __shared__ float sFus[32][66];                // padded: conflict-free col reads
    __shared__ float sF[2][256];                  // PNA feats
    __shared__ float sP[2][2][64];                // k-split partials
    __shared__ float sP7[2][8][8];                // predict partials
    __shared__ float sH1[2][64];
    __shared__ float sH2[2][64];
    __shared__ float sGrp[2][64];
    __shared__ float sActe[2][64];
    __shared__ float sHH[2][8];

    const int t    = threadIdx.x;
    const int blk  = blockIdx.x;
    const int lane = t & 63;
    const int w    = t >> 6;        // wave id = e-block (0..3)
    const int lr   = lane & 15;     // A row (seq) / B,D col selector
    const int lb   = lane >> 4;     // k-block / D row-block selector

    // --- this block's indices (contiguous 1600 ints, coalesced)
    for (int i = t; i < 32 * LL; i += 256) sIdx[i] = act_seqs[blk * (32 * LL) + i];
    // --- gather row ids: pair p (= global b*16+m = blk*32+p), j=0 member, 1..32 nbrs
    for (int i = t; i < 32 * 33; i += 256) {
        const int p = i / 33, j = i - p * 33;
        const int base = blk * 32 + p;
        sNbr[i] = (j == 0) ? members[base] : neighbors[base * KK + j - 1];
    }
    // --- stage act_e for both batches (prologue: latency hidden under setup)
    if (t < 128) {
        const int q = t >> 6, e = t & 63;
        sActe[q][e] = act_table[(size_t)act_inputs[blk * 2 + q] * EE + e];
    }

    // per-gate exp2 fold scales (i,f,o: -log2e; g: +2*log2e)
    const float L2E = 1.44269504088896f;
    float gscale[4];
    gscale[0] = -L2E; gscale[1] = -L2E; gscale[2] = 2.0f * L2E; gscale[3] = -L2E;

    // --- weights -> register B-frags, SCALED. gates = in @ W^T => B[k][j]=W[j][k].
    short8 Bf[2][4][2];   // [mat(ih,hh)][gate][ks]
    #pragma unroll
    for (int mat = 0; mat < 2; ++mat) {
        const float* W = mat ? W_hh : W_ih;
        #pragma unroll
        for (int g = 0; g < 4; ++g) {
            const int j = g * 64 + w * 16 + lr;
            const float sc = gscale[g];
            #pragma unroll
            for (int ks = 0; ks < 2; ++ks) {
                const float4* p = reinterpret_cast<const float4*>(&W[(size_t)j * 64 + ks * 32 + lb * 8]);
                float4 v0 = p[0], v1 = p[1];
                uint4 o;
                o.x = cvt_pk_bf16(sc * v0.x, sc * v0.y);
                o.y = cvt_pk_bf16(sc * v0.z, sc * v0.w);
                o.z = cvt_pk_bf16(sc * v1.x, sc * v1.y);
                o.w = cvt_pk_bf16(sc * v1.z, sc * v1.w);
                Bf[mat][g][ks] = __builtin_bit_cast(short8, o);
            }
        }
    }
    // --- gcn_W -> register B-frags (epilogue MFMA), unscaled bf16 RNE
    short8 Bg[2];
    #pragma unroll
    for (int ks = 0; ks < 2; ++ks) {
        const int j = w * 16 + lr;
        const float4* p = reinterpret_cast<const float4*>(&gcn_W[(size_t)j * 64 + ks * 32 + lb * 8]);
        float4 v0 = p[0], v1 = p[1];
        uint4 o;
        o.x = cvt_pk_bf16(v0.x, v0.y);
        o.y = cvt_pk_bf16(v0.z, v0.w);
        o.z = cvt_pk_bf16(v1.x, v1.y);
        o.w = cvt_pk_bf16(v1.z, v1.w);
        Bg[ks] = __builtin_bit_cast(short8, o);
    }
    const float gb = gcn_b[w * 16 + lr];

    float bias[4];
    #pragma unroll
    for (int g = 0; g < 4; ++g) {
        const int j = g * 64 + w * 16 + lr;
        bias[g] = gscale[g] * (b_ih[j] + b_hh[j]);
    }

    float hA[4], cA[4], hB[4], cB[4];
    #pragma unroll
    for (int r = 0; r < 4; ++r) { hA[r] = 0.0f; cA[r] = 0.0f; hB[r] = 0.0f; cB[r] = 0.0f; }

    // zero buf0 (tiles 0,1 = 4096 B = 256 x uint4)
    reinterpret_cast<uint4*>(sH)[t] = make_uint4(0u, 0u, 0u, 0u);
    __syncthreads();   // sIdx + sNbr + sActe + sH buf0 visible (once)

    // --- gather lane mapping: pair p = t>>3 owns row blk*32+p; chunk ec = t&7
    const int gpair = t >> 3;
    const int gec   = t & 7;
    const float* gut = user_table + (size_t)gec * 8;
    float gacc[8];
    #pragma unroll
    for (int q = 0; q < 8; ++q) gacc[q] = 0.0f;
    // pre-issue gather row 0 (BEFORE x pre-loads: older in vmcnt FIFO)
    float4 gld0, gld1;
    {
        const int gi = sNbr[gpair * 33 + 0];
        const float4* gp = reinterpret_cast<const float4*>(gut + (size_t)gi * EE);
        gld0 = gp[0]; gld1 = gp[1];
    }

    // --- x gather: lane's frag = bytes [id*128 + lb*16] and +64.
    const char* tbl8 = reinterpret_cast<const char*>(act_bf) + lb * 16;
    const int ibA = lr * LL;           // chain A: seq lr
    const int ibB = (16 + lr) * LL;    // chain B: seq 16+lr

    int idA = sIdx[ibA + 0], idB = sIdx[ibB + 0];
    short8 axA0 = *reinterpret_cast<const short8*>(tbl8 + (size_t)idA * 128);
    short8 axA1 = *reinterpret_cast<const short8*>(tbl8 + (size_t)idA * 128 + 64);
    short8 axB0 = *reinterpret_cast<const short8*>(tbl8 + (size_t)idB * 128);
    short8 axB1 = *reinterpret_cast<const short8*>(tbl8 + (size_t)idB * 128 + 64);
    idA = sIdx[ibA + 1]; idB = sIdx[ibB + 1];

    // LDS byte offsets (loop-invariant)
    const int offA0 = lr * 128 + ((lb ^ (lr & 7)) << 4);
    const int offA1 = lr * 128 + (((lb + 4) ^ (lr & 7)) << 4);
    int hw_off[4];
    #pragma unroll
    for (int r = 0; r < 4; ++r) {
        const int s = lb * 4 + r, e = w * 16 + lr;
        hw_off[r] = s * 128 + ((((e >> 3) ^ (s & 7)) << 4)) + (e & 7) * 2;
    }
    char* const sHb = reinterpret_cast<char*>(sH);

    #pragma unroll 2
    for (int step = 0; step < LL; ++step) {
        const int cb  = (step & 1) << 12;   // current buf base: 0 or 4096
        const int nb_ = cb ^ 4096;          // next buf base

        // 0. fused GCN gather: accumulate row `step` (loaded last step),
        //    then issue row step+1 (BEFORE x prefetch -> older in vmcnt FIFO).
        if (step < 33) {
            gacc[0] += gld0.x; gacc[1] += gld0.y; gacc[2] += gld0.z; gacc[3] += gld0.w;
            gacc[4] += gld1.x; gacc[5] += gld1.y; gacc[6] += gld1.z; gacc[7] += gld1.w;
            if (step < 32) {
                const int gi = sNbr[gpair * 33 + step + 1];
                const float4* gp = reinterpret_cast<const float4*>(gut + (size_t)gi * EE);
                gld0 = gp[0]; gld1 = gp[1];
            }
        }

        // 1. issue x prefetch for step+1 (stays in flight across the barrier)
        short8 nxA0 = *reinterpret_cast<const short8*>(tbl8 + (size_t)idA * 128);
        short8 nxA1 = *reinterpret_cast<const short8*>(tbl8 + (size_t)idA * 128 + 64);
        short8 nxB0 = *reinterpret_cast<const short8*>(tbl8 + (size_t)idB * 128);
        short8 nxB1 = *reinterpret_cast<const short8*>(tbl8 + (size_t)idB * 128 + 64);
        {
            const int s2 = (step + 2 < LL) ? (step + 2) : (LL - 1);
            idA = sIdx[ibA + s2]; idB = sIdx[ibB + s2];
        }

        // 2. read h A-frags for both chains (swizzled, conflict-free)
        short8 ahA0 = *reinterpret_cast<const short8*>(sHb + cb + offA0);
        short8 ahA1 = *reinterpret_cast<const short8*>(sHb + cb + offA1);
        short8 ahB0 = *reinterpret_cast<const short8*>(sHb + cb + 2048 + offA0);
        short8 ahB1 = *reinterpret_cast<const short8*>(sHb + cb + 2048 + offA1);

        // 3. acc = scaled_bias + x @ sWih^T + h @ sWhh^T  (2 independent chains)
        v4f accA[4], accB[4];
        #pragma unroll
        for (int g = 0; g < 4; ++g) {
            v4f a; a[0] = bias[g]; a[1] = bias[g]; a[2] = bias[g]; a[3] = bias[g];
            accA[g] = a; accB[g] = a;
        }
        #pragma unroll
        for (int g = 0; g < 4; ++g) {
            accA[g] = __builtin_amdgcn_mfma_f32_16x16x32_bf16(axA0, Bf[0][g][0], accA[g], 0, 0, 0);
            accA[g] = __builtin_amdgcn_mfma_f32_16x16x32_bf16(axA1, Bf[0][g][1], accA[g], 0, 0, 0);
            accA[g] = __builtin_amdgcn_mfma_f32_16x16x32_bf16(ahA0, Bf[1][g][0], accA[g], 0, 0, 0);
            accA[g] = __builtin_amdgcn_mfma_f32_16x16x32_bf16(ahA1, Bf[1][g][1], accA[g], 0, 0, 0);
        }
        #pragma unroll
        for (int g = 0; g < 4; ++g) {
            accB[g] = __builtin_amdgcn_mfma_f32_16x16x32_bf16(axB0, Bf[0][g][0], accB[g], 0, 0, 0);
            accB[g] = __builtin_amdgcn_mfma_f32_16x16x32_bf16(axB1, Bf[0][g][1], accB[g], 0, 0, 0);
            accB[g] = __builtin_amdgcn_mfma_f32_16x16x32_bf16(ahB0, Bf[1][g][0], accB[g], 0, 0, 0);
            accB[g] = __builtin_amdgcn_mfma_f32_16x16x32_bf16(ahB1, Bf[1][g][1], accB[g], 0, 0, 0);
        }

        // 4. gate nonlinearities (exp2 args straight from MFMA) + h writes
        {
            char* SH = sHb + nb_;
            #pragma unroll
            for (int r = 0; r < 4; ++r) {
                const float si = rcpf(1.0f + exp2_fast(accA[0][r]));
                const float sf = rcpf(1.0f + exp2_fast(accA[1][r]));
                const float tg = fmaf(-2.0f, rcpf(1.0f + exp2_fast(accA[2][r])), 1.0f);
                const float so = rcpf(1.0f + exp2_fast(accA[3][r]));
                const float cc = fmaf(sf, cA[r], si * tg);
                cA[r] = cc;
                hA[r] = so * fmaf(-2.0f, rcpf(1.0f + exp2_fast(cc * (2.0f * L2E))), 1.0f);
            }
            const unsigned a01 = cvt_pk_bf16(hA[0], hA[1]);
            const unsigned a23 = cvt_pk_bf16(hA[2], hA[3]);
            *reinterpret_cast<short*>(SH + hw_off[0]) = (short)(a01 & 0xFFFF);
            *reinterpret_cast<short*>(SH + hw_off[1]) = (short)(a01 >> 16);
            *reinterpret_cast<short*>(SH + hw_off[2]) = (short)(a23 & 0xFFFF);
            *reinterpret_cast<short*>(SH + hw_off[3]) = (short)(a23 >> 16);
            SH += 2048;
            #pragma unroll
            for (int r = 0; r < 4; ++r) {
                const float si = rcpf(1.0f + exp2_fast(accB[0][r]));
                const float sf = rcpf(1.0f + exp2_fast(accB[1][r]));
                const float tg = fmaf(-2.0f, rcpf(1.0f + exp2_fast(accB[2][r])), 1.0f);
                const float so = rcpf(1.0f + exp2_fast(accB[3][r]));
                const float cc = fmaf(sf, cB[r], si * tg);
                cB[r] = cc;
                hB[r] = so * fmaf(-2.0f, rcpf(1.0f + exp2_fast(cc * (2.0f * L2E))), 1.0f);
            }
            const unsigned b01 = cvt_pk_bf16(hB[0], hB[1]);
            const unsigned b23 = cvt_pk_bf16(hB[2], hB[3]);
            *reinterpret_cast<short*>(SH + hw_off[0]) = (short)(b01 & 0xFFFF);
            *reinterpret_cast<short*>(SH + hw_off[1]) = (short)(b01 >> 16);
            *reinterpret_cast<short*>(SH + hw_off[2]) = (short)(b23 & 0xFFFF);
            *reinterpret_cast<short*>(SH + hw_off[3]) = (short)(b23 >> 16);
        }

        // 5. LDS-only barrier (x + gather loads stay in flight)
        block_sync_lds();

        // 6. roll prefetch regs (unroll-2 lets the allocator rename these)
        axA0 = nxA0; axA1 = nxA1; axB0 = nxB0; axB1 = nxB1;
    }

    // ======================= FUSED POST EPILOGUE =======================
    // batches q=0,1 -> global b = blk*2 + q; local pair p = q*16 + m.

    // 1. stage agg/33 as bf16 into dead sH tiles 0,1 (same swizzle as h):
    //    row = gpair&15, tile = gpair>>4, chunk = gec (one ds_write_b128).
    {
        const float sc = 1.0f / 33.0f;
        uint4 pk;
        pk.x = cvt_pk_bf16(gacc[0] * sc, gacc[1] * sc);
        pk.y = cvt_pk_bf16(gacc[2] * sc, gacc[3] * sc);
        pk.z = cvt_pk_bf16(gacc[4] * sc, gacc[5] * sc);
        pk.w = cvt_pk_bf16(gacc[6] * sc, gacc[7] * sc);
        const int row = gpair & 15;
        const int off = ((gpair >> 4) << 11) + row * 128 + ((gec ^ (row & 7)) << 4);
        *reinterpret_cast<uint4*>(sHb + off) = pk;
    }
    __syncthreads();

    // 2. m_gcn = relu(agg @ gcn_W^T + b) via MFMA; fus = h + m_gcn.
    //    D-layout (row=lb*4+r, col=w*16+lr) == hA/hB layout -> register-local.
    {
        short8 agA0 = *reinterpret_cast<const short8*>(sHb + offA0);
        short8 agA1 = *reinterpret_cast<const short8*>(sHb + offA1);
        short8 agB0 = *reinterpret_cast<const short8*>(sHb + 2048 + offA0);
        short8 agB1 = *reinterpret_cast<const short8*>(sHb + 2048 + offA1);
        v4f z4 = {0.0f, 0.0f, 0.0f, 0.0f};
        v4f gA = __builtin_amdgcn_mfma_f32_16x16x32_bf16(agA0, Bg[0], z4, 0, 0, 0);
        gA = __builtin_amdgcn_mfma_f32_16x16x32_bf16(agA1, Bg[1], gA, 0, 0, 0);
        v4f gB = __builtin_amdgcn_mfma_f32_16x16x32_bf16(agB0, Bg[0], z4, 0, 0, 0);
        gB = __builtin_amdgcn_mfma_f32_16x16x32_bf16(agB1, Bg[1], gB, 0, 0, 0);
        const int e = w * 16 + lr;
        #pragma unroll
        for (int r = 0; r < 4; ++r) {
            sFus[lb * 4 + r][e]      = hA[r] + fmaxf(gA[r] + gb, 0.0f);
            sFus[16 + lb * 4 + r][e] = hB[r] + fmaxf(gB[r] + gb, 0.0f);
        }
    }
    __syncthreads();

    // 3. PNA reduce over M (amp = 1 exactly)
    if (t < 128) {
        const int q = t >> 6, e = t & 63;
        float mn = 0.0f, mx = -INFINITY;
        #pragma unroll
        for (int m = 0; m < MM; ++m) { float v = sFus[q * 16 + m][e]; mn += v; mx = fmaxf(mx, v); }
        mn *= (1.0f / 16.0f);
        sF[q][e] = mn; sF[q][64 + e] = mx; sF[q][128 + e] = mn; sF[q][192 + e] = mx;
    }
    __syncthreads();

    // 4. h1 = relu(feats @ pna_W1 + b1): 256->64, k split 2x128 over 256 thr
    {
        const int q = t >> 7, kh = (t >> 6) & 1, j = t & 63;
        float p = 0.0f;
        const float* Wp = pna_W1 + (size_t)(kh * 128) * 64 + j;
        const float* fp = &sF[q][kh * 128];
        #pragma unroll 16
        for (int k = 0; k < 128; ++k) p = fmaf(fp[k], Wp[(size_t)k * 64], p);
        sP[q][kh][j] = p;
    }
    __syncthreads();
    if (t < 128) {
        const int q = t >> 6, j = t & 63;
        sH1[q][j] = fmaxf(pna_b1[j] + sP[q][0][j] + sP[q][1][j], 0.0f);
    }
    __syncthreads();

    // 5. h2 = relu(h1 @ pna_W2 + b2): k split 2x32 over 256 thr
    {
        const int q = t >> 7, kh = (t >> 6) & 1, j = t & 63;
        float p = 0.0f;
        #pragma unroll
        for (int k = 0; k < 32; ++k)
            p = fmaf(sH1[q][kh * 32 + k], pna_W2[(size_t)(kh * 32 + k) * 64 + j], p);
        sP[q][kh][j] = p;
    }
    __syncthreads();
    if (t < 128) {
        const int q = t >> 6, j = t & 63;
        sH2[q][j] = fmaxf(pna_b2[j] + sP[q][0][j] + sP[q][1][j], 0.0f);
    }
    __syncthreads();

    // 6. grp = h2 @ pna_W3 + b3: k split 2x32 over 256 thr
    {
        const int q = t >> 7, kh = (t >> 6) & 1, j = t & 63;
        float p = 0.0f;
        #pragma unroll
        for (int k = 0; k < 32; ++k)
            p = fmaf(sH2[q][kh * 32 + k], pna_W3[(size_t)(kh * 32 + k) * 64 + j], p);
        sP[q][kh][j] = p;
    }
    __syncthreads();
    if (t < 128) {
        const int q = t >> 6, j = t & 63;
        sGrp[q][j] = pna_b3[j] + sP[q][0][j] + sP[q][1][j];
    }
    __syncthreads();

    // 7. predict layer 1: 128 threads, k split 8x24; then 16-thread combine
    if (t < 128) {
        const int q = t >> 6, kg = (t >> 3) & 7, j = t & 7;
        float a = 0.0f;
        #pragma unroll
        for (int kk = 0; kk < 24; ++kk) {
            const int k = kg * 24 + kk;
            const float cv = (k < 64) ? sGrp[q][k] * sActe[q][k]
                                      : ((k < 128) ? sGrp[q][k - 64] : sActe[q][k - 128]);
            a = fmaf(cv, pred_W1[k * 8 + j], a);
        }
        sP7[q][kg][j] = a;
    }
    __syncthreads();
    if (t < 16) {
        const int q = t >> 3, j = t & 7;
        float a = pred_b1[j];
        #pragma unroll
        for (int kg = 0; kg < 8; ++kg) a += sP7[q][kg][j];
        sHH[q][j] = fmaxf(a, 0.0f);
    }
    __syncthreads();
    if (t < 2) {
        float y = pred_b2[0];
        #pragma unroll
        for (int jj = 0; jj < 8; ++jj) y = fmaf(sHH[t][jj], pred_W2[jj], y);
        out[blk * 2 + t] = 1.0f / (1.0f + expf(-y));
    }
}

extern "C" void kernel_launch(void* const* d_in, const int* in_sizes, int n_in,
                              void* d_out, int out_size, void* d_ws, size_t ws_size,
                              hipStream_t stream) {
    const int*   members    = (const int*)d_in[0];
    const int*   neighbors  = (const int*)d_in[1];
    const int*   act_inputs = (const int*)d_in[2];
    const int*   act_seqs   = (const int*)d_in[3];
    const float* act_table  = (const float*)d_in[4];
    const float* user_table = (const float*)d_in[5];
    const float* W_ih       = (const float*)d_in[6];
    const float* W_hh       = (const float*)d_in[7];
    const float* b_ih       = (const float*)d_in[8];
    const float* b_hh       = (const float*)d_in[9];
    const float* gcn_W      = (const float*)d_in[10];
    const float* gcn_b      = (const float*)d_in[11];
    const float* pna_W1     = (const float*)d_in[12];
    const float* pna_b1     = (const float*)d_in[13];
    const float* pna_W2     = (const float*)d_in[14];
    const float* pna_b2     = (const float*)d_in[15];
    const float* pna_W3     = (const float*)d_in[16];
    const float* pna_b3     = (const float*)d_in[17];
    const float* pred_W1    = (const float*)d_in[18];
    const float* pred_b1    = (const float*)d_in[19];
    const float* pred_W2    = (const float*)d_in[20];
    const float* pred_b2    = (const float*)d_in[21];

    unsigned short* act_bf = (unsigned short*)d_ws;   // 12.8 MB bf16 table

    cvt_table<<<dim3((NACT * EE / 8 + 255) / 256), dim3(256), 0, stream>>>(
        act_table, (unsigned*)act_bf);

    lstm_fused<<<dim3(512), dim3(256), 0, stream>>>(
        act_seqs, act_bf, members, neighbors, user_table,
        W_ih, W_hh, b_ih, b_hh,
        act_inputs, act_table,
        gcn_W, gcn_b, pna_W1, pna_b1, pna_W2, pna_b2, pna_W3, pna_b3,
        pred_W1, pred_b1, pred_W2, pred_b2, (float*)d_out);
}

// Round 16
// 105.140 us; speedup vs baseline: 1.6986x; 1.0083x over previous
//
#include <hip/hip_runtime.h>
#include <hip/hip_bf16.h>
#include <math.h>

// Problem constants (match reference)
#define BB   1024
#define MM   16
#define KK   32
#define LL   50
#define EE   64
#define NACT 100000

typedef __attribute__((ext_vector_type(8))) short short8;
typedef float v4f __attribute__((ext_vector_type(4)));

__device__ __forceinline__ float rcpf(float x) { return __builtin_amdgcn_rcpf(x); }
// native 2^x (v_exp_f32 IS exp2)
__device__ __forceinline__ float exp2_fast(float x) {
    float r;
    asm("v_exp_f32 %0, %1" : "=v"(r) : "v"(x));
    return r;
}

// packed f32x2 -> bf16x2 (lo->low16, hi->high16), RNE
__device__ __forceinline__ unsigned cvt_pk_bf16(float lo, float hi) {
    unsigned r;
    asm("v_cvt_pk_bf16_f32 %0, %1, %2" : "=v"(r) : "v"(lo), "v"(hi));
    return r;
}

// Block-wide barrier that does NOT drain vmcnt: LDS writes are made visible
// (lgkmcnt(0)) but global prefetch loads stay in flight across the barrier.
__device__ __forceinline__ void block_sync_lds() {
    __builtin_amdgcn_sched_barrier(0);
    asm volatile("s_waitcnt lgkmcnt(0)" ::: "memory");
    __builtin_amdgcn_s_barrier();
    __builtin_amdgcn_sched_barrier(0);
}

// ---------------------------------------------------------------------------
// Pre-pass: act_table f32 -> bf16 (row-major, same layout). 8 floats/thread.
// ---------------------------------------------------------------------------
__global__ __launch_bounds__(256)
void cvt_table(const float* __restrict__ src, unsigned* __restrict__ dst)
{
    const int i = blockIdx.x * 256 + threadIdx.x;          // unit = 8 floats
    if (i < (NACT * EE) / 8) {
        const float4* s = reinterpret_cast<const float4*>(src) + (size_t)i * 2;
        float4 a = s[0], b = s[1];
        uint4 o;
        o.x = cvt_pk_bf16(a.x, a.y);
        o.y = cvt_pk_bf16(a.z, a.w);
        o.z = cvt_pk_bf16(b.x, b.y);
        o.w = cvt_pk_bf16(b.z, b.w);
        reinterpret_cast<uint4*>(dst)[i] = o;
    }
}

// ---------------------------------------------------------------------------
// FULLY-FUSED kernel (r15 structure) + cross-step x-GEMM pipelining:
// the x-contribution to step s+1's gates (bias + x@Wih, 8 MFMA/chain) is
// computed during step s AFTER the nonlinearity -- it has no h dependency,
// so the MFMA pipe fills while the VALU runs trans ops and while the wave
// waits at the barrier. The post-barrier dependent chain shrinks to
// ds_read h -> 2 MFMAs -> nonlin. FP accumulation order is UNCHANGED
// (bias -> x-MFMAs -> h-MFMAs) => bit-identical output to r15.
// Everything else (gather fusion, exp2 fold, MFMA epilogue) is r15.
// ---------------------------------------------------------------------------
__global__ __launch_bounds__(256, 2)
void lstm_fused(const int* __restrict__ act_seqs, const unsigned short* __restrict__ act_bf,
                const int* __restrict__ members, const int* __restrict__ neighbors,
                const float* __restrict__ user_table,
                const float* __restrict__ W_ih, const float* __restrict__ W_hh,
                const float* __restrict__ b_ih, const float* __restrict__ b_hh,
                const int* __restrict__ act_inputs, const float* __restrict__ act_table,
                const float* __restrict__ gcn_W, const float* __restrict__ gcn_b,
                const float* __restrict__ pna_W1, const float* __restrict__ pna_b1,
                const float* __restrict__ pna_W2, const float* __restrict__ pna_b2,
                const float* __restrict__ pna_W3, const float* __restrict__ pna_b3,
                const float* __restrict__ pred_W1, const float* __restrict__ pred_b1,
                const float* __restrict__ pred_W2, const float* __restrict__ pred_b2,
                float* __restrict__ out)
{
    // --- loop-phase LDS
    __shared__ __align__(16) short sH[4][1024];   // h dbuf (bf16 swizzled), 8 KB
    __shared__ int sIdx[32 * LL];                 // 6.4 KB
    __shared__ int sNbr[32 * 33];                 // 4.2 KB
    // --- epilogue LDS
    __shared__ float sFus[32][66];                // padded: conflict-free col reads
    __shared__ float sF[2][256];                  // PNA feats
    __shared__ float sP[2][2][64];                // k-split partials
    __shared__ float sP7[2][8][8];                // predict partials
    __shared__ float sH1[2][64];
    __shared__ float sH2[2][64];
    __shared__ float sGrp[2][64];
    __shared__ float sActe[2][64];
    __shared__ float sHH[2][8];

    const int t    = threadIdx.x;
    const int blk  = blockIdx.x;
    const int lane = t & 63;
    const int w    = t >> 6;        // wave id = e-block (0..3)
    const int lr   = lane & 15;     // A row (seq) / B,D col selector
    const int lb   = lane >> 4;     // k-block / D row-block selector

    // --- this block's indices (contiguous 1600 ints, coalesced)
    for (int i = t; i < 32 * LL; i += 256) sIdx[i] = act_seqs[blk * (32 * LL) + i];
    // --- gather row ids: pair p (= global b*16+m = blk*32+p), j=0 member, 1..32 nbrs
    for (int i = t; i < 32 * 33; i += 256) {
        const int p = i / 33, j = i - p * 33;
        const int base = blk * 32 + p;
        sNbr[i] = (j == 0) ? members[base] : neighbors[base * KK + j - 1];
    }
    // --- stage act_e for both batches (prologue: latency hidden under setup)
    if (t < 128) {
        const int q = t >> 6, e = t & 63;
        sActe[q][e] = act_table[(size_t)act_inputs[blk * 2 + q] * EE + e];
    }

    // per-gate exp2 fold scales (i,f,o: -log2e; g: +2*log2e)
    const float L2E = 1.44269504088896f;
    float gscale[4];
    gscale[0] = -L2E; gscale[1] = -L2E; gscale[2] = 2.0f * L2E; gscale[3] = -L2E;

    // --- weights -> register B-frags, SCALED. gates = in @ W^T => B[k][j]=W[j][k].
    short8 Bf[2][4][2];   // [mat(ih,hh)][gate][ks]
    #pragma unroll
    for (int mat = 0; mat < 2; ++mat) {
        const float* W = mat ? W_hh : W_ih;
        #pragma unroll
        for (int g = 0; g < 4; ++g) {
            const int j = g * 64 + w * 16 + lr;
            const float sc = gscale[g];
            #pragma unroll
            for (int ks = 0; ks < 2; ++ks) {
                const float4* p = reinterpret_cast<const float4*>(&W[(size_t)j * 64 + ks * 32 + lb * 8]);
                float4 v0 = p[0], v1 = p[1];
                uint4 o;
                o.x = cvt_pk_bf16(sc * v0.x, sc * v0.y);
                o.y = cvt_pk_bf16(sc * v0.z, sc * v0.w);
                o.z = cvt_pk_bf16(sc * v1.x, sc * v1.y);
                o.w = cvt_pk_bf16(sc * v1.z, sc * v1.w);
                Bf[mat][g][ks] = __builtin_bit_cast(short8, o);
            }
        }
    }
    // --- gcn_W -> register B-frags (epilogue MFMA), unscaled bf16 RNE
    short8 Bg[2];
    #pragma unroll
    for (int ks = 0; ks < 2; ++ks) {
        const int j = w * 16 + lr;
        const float4* p = reinterpret_cast<const float4*>(&gcn_W[(size_t)j * 64 + ks * 32 + lb * 8]);
        float4 v0 = p[0], v1 = p[1];
        uint4 o;
        o.x = cvt_pk_bf16(v0.x, v0.y);
        o.y = cvt_pk_bf16(v0.z, v0.w);
        o.z = cvt_pk_bf16(v1.x, v1.y);
        o.w = cvt_pk_bf16(v1.z, v1.w);
        Bg[ks] = __builtin_bit_cast(short8, o);
    }
    const float gb = gcn_b[w * 16 + lr];

    float bias[4];
    #pragma unroll
    for (int g = 0; g < 4; ++g) {
        const int j = g * 64 + w * 16 + lr;
        bias[g] = gscale[g] * (b_ih[j] + b_hh[j]);
    }

    float hA[4], cA[4], hB[4], cB[4];
    #pragma unroll
    for (int r = 0; r < 4; ++r) { hA[r] = 0.0f; cA[r] = 0.0f; hB[r] = 0.0f; cB[r] = 0.0f; }

    // zero buf0 (tiles 0,1 = 4096 B = 256 x uint4)
    reinterpret_cast<uint4*>(sH)[t] = make_uint4(0u, 0u, 0u, 0u);
    __syncthreads();   // sIdx + sNbr + sActe + sH buf0 visible (once)

    // --- gather lane mapping: pair p = t>>3 owns row blk*32+p; chunk ec = t&7
    const int gpair = t >> 3;
    const int gec   = t & 7;
    const float* gut = user_table + (size_t)gec * 8;
    float gacc[8];
    #pragma unroll
    for (int q = 0; q < 8; ++q) gacc[q] = 0.0f;
    // pre-issue gather row 0 (BEFORE x pre-loads: older in vmcnt FIFO)
    float4 gld0, gld1;
    {
        const int gi = sNbr[gpair * 33 + 0];
        const float4* gp = reinterpret_cast<const float4*>(gut + (size_t)gi * EE);
        gld0 = gp[0]; gld1 = gp[1];
    }

    // --- x gather: lane's frag = bytes [id*128 + lb*16] and +64.
    const char* tbl8 = reinterpret_cast<const char*>(act_bf) + lb * 16;
    const int ibA = lr * LL;           // chain A: seq lr
    const int ibB = (16 + lr) * LL;    // chain B: seq 16+lr

    // prologue: load x_0, compute xacc for step 0; load x_1 -> px; idx -> x_2
    int idA = sIdx[ibA + 0], idB = sIdx[ibB + 0];
    short8 c0A0 = *reinterpret_cast<const short8*>(tbl8 + (size_t)idA * 128);
    short8 c0A1 = *reinterpret_cast<const short8*>(tbl8 + (size_t)idA * 128 + 64);
    short8 c0B0 = *reinterpret_cast<const short8*>(tbl8 + (size_t)idB * 128);
    short8 c0B1 = *reinterpret_cast<const short8*>(tbl8 + (size_t)idB * 128 + 64);
    idA = sIdx[ibA + 1]; idB = sIdx[ibB + 1];
    short8 pxA0 = *reinterpret_cast<const short8*>(tbl8 + (size_t)idA * 128);
    short8 pxA1 = *reinterpret_cast<const short8*>(tbl8 + (size_t)idA * 128 + 64);
    short8 pxB0 = *reinterpret_cast<const short8*>(tbl8 + (size_t)idB * 128);
    short8 pxB1 = *reinterpret_cast<const short8*>(tbl8 + (size_t)idB * 128 + 64);
    idA = sIdx[ibA + 2]; idB = sIdx[ibB + 2];

    v4f xaccA[4], xaccB[4];
    #pragma unroll
    for (int g = 0; g < 4; ++g) {
        v4f a; a[0] = bias[g]; a[1] = bias[g]; a[2] = bias[g]; a[3] = bias[g];
        a = __builtin_amdgcn_mfma_f32_16x16x32_bf16(c0A0, Bf[0][g][0], a, 0, 0, 0);
        xaccA[g] = __builtin_amdgcn_mfma_f32_16x16x32_bf16(c0A1, Bf[0][g][1], a, 0, 0, 0);
        v4f b; b[0] = bias[g]; b[1] = bias[g]; b[2] = bias[g]; b[3] = bias[g];
        b = __builtin_amdgcn_mfma_f32_16x16x32_bf16(c0B0, Bf[0][g][0], b, 0, 0, 0);
        xaccB[g] = __builtin_amdgcn_mfma_f32_16x16x32_bf16(c0B1, Bf[0][g][1], b, 0, 0, 0);
    }

    // LDS byte offsets (loop-invariant)
    const int offA0 = lr * 128 + ((lb ^ (lr & 7)) << 4);
    const int offA1 = lr * 128 + (((lb + 4) ^ (lr & 7)) << 4);
    int hw_off[4];
    #pragma unroll
    for (int r = 0; r < 4; ++r) {
        const int s = lb * 4 + r, e = w * 16 + lr;
        hw_off[r] = s * 128 + ((((e >> 3) ^ (s & 7)) << 4)) + (e & 7) * 2;
    }
    char* const sHb = reinterpret_cast<char*>(sH);

    #pragma unroll 2
    for (int step = 0; step < LL; ++step) {
        const int cb  = (step & 1) << 12;   // current buf base: 0 or 4096
        const int nb_ = cb ^ 4096;          // next buf base

        // 0. fused GCN gather: accumulate row `step` (loaded last step),
        //    then issue row step+1 (BEFORE x prefetch -> older in vmcnt FIFO).
        if (step < 33) {
            gacc[0] += gld0.x; gacc[1] += gld0.y; gacc[2] += gld0.z; gacc[3] += gld0.w;
            gacc[4] += gld1.x; gacc[5] += gld1.y; gacc[6] += gld1.z; gacc[7] += gld1.w;
            if (step < 32) {
                const int gi = sNbr[gpair * 33 + step + 1];
                const float4* gp = reinterpret_cast<const float4*>(gut + (size_t)gi * EE);
                gld0 = gp[0]; gld1 = gp[1];
            }
        }

        // 1. issue x prefetch for step+2 (stays in flight across the barrier)
        short8 nxA0 = *reinterpret_cast<const short8*>(tbl8 + (size_t)idA * 128);
        short8 nxA1 = *reinterpret_cast<const short8*>(tbl8 + (size_t)idA * 128 + 64);
        short8 nxB0 = *reinterpret_cast<const short8*>(tbl8 + (size_t)idB * 128);
        short8 nxB1 = *reinterpret_cast<const short8*>(tbl8 + (size_t)idB * 128 + 64);
        {
            const int s2 = (step + 3 < LL) ? (step + 3) : (LL - 1);
            idA = sIdx[ibA + s2]; idB = sIdx[ibB + s2];
        }

        // 2. read h A-frags for both chains (swizzled, conflict-free)
        short8 ahA0 = *reinterpret_cast<const short8*>(sHb + cb + offA0);
        short8 ahA1 = *reinterpret_cast<const short8*>(sHb + cb + offA1);
        short8 ahB0 = *reinterpret_cast<const short8*>(sHb + cb + 2048 + offA0);
        short8 ahB1 = *reinterpret_cast<const short8*>(sHb + cb + 2048 + offA1);

        // 3. acc = xacc (bias + x-part, computed last step) + h @ sWhh^T
        //    -> only 2-deep dependent MFMA chain after the barrier.
        v4f accA[4], accB[4];
        #pragma unroll
        for (int g = 0; g < 4; ++g) {
            v4f a = __builtin_amdgcn_mfma_f32_16x16x32_bf16(ahA0, Bf[1][g][0], xaccA[g], 0, 0, 0);
            accA[g] = __builtin_amdgcn_mfma_f32_16x16x32_bf16(ahA1, Bf[1][g][1], a, 0, 0, 0);
            v4f b = __builtin_amdgcn_mfma_f32_16x16x32_bf16(ahB0, Bf[1][g][0], xaccB[g], 0, 0, 0);
            accB[g] = __builtin_amdgcn_mfma_f32_16x16x32_bf16(ahB1, Bf[1][g][1], b, 0, 0, 0);
        }

        // 4. gate nonlinearities (exp2 args straight from MFMA) + h writes
        {
            char* SH = sHb + nb_;
            #pragma unroll
            for (int r = 0; r < 4; ++r) {
                const float si = rcpf(1.0f + exp2_fast(accA[0][r]));
                const float sf = rcpf(1.0f + exp2_fast(accA[1][r]));
                const float tg = fmaf(-2.0f, rcpf(1.0f + exp2_fast(accA[2][r])), 1.0f);
                const float so = rcpf(1.0f + exp2_fast(accA[3][r]));
                const float cc = fmaf(sf, cA[r], si * tg);
                cA[r] = cc;
                hA[r] = so * fmaf(-2.0f, rcpf(1.0f + exp2_fast(cc * (2.0f * L2E))), 1.0f);
            }
            const unsigned a01 = cvt_pk_bf16(hA[0], hA[1]);
            const unsigned a23 = cvt_pk_bf16(hA[2], hA[3]);
            *reinterpret_cast<short*>(SH + hw_off[0]) = (short)(a01 & 0xFFFF);
            *reinterpret_cast<short*>(SH + hw_off[1]) = (short)(a01 >> 16);
            *reinterpret_cast<short*>(SH + hw_off[2]) = (short)(a23 & 0xFFFF);
            *reinterpret_cast<short*>(SH + hw_off[3]) = (short)(a23 >> 16);
            SH += 2048;
            #pragma unroll
            for (int r = 0; r < 4; ++r) {
                const float si = rcpf(1.0f + exp2_fast(accB[0][r]));
                const float sf = rcpf(1.0f + exp2_fast(accB[1][r]));
                const float tg = fmaf(-2.0f, rcpf(1.0f + exp2_fast(accB[2][r])), 1.0f);
                const float so = rcpf(1.0f + exp2_fast(accB[3][r]));
                const float cc = fmaf(sf, cB[r], si * tg);
                cB[r] = cc;
                hB[r] = so * fmaf(-2.0f, rcpf(1.0f + exp2_fast(cc * (2.0f * L2E))), 1.0f);
            }
            const unsigned b01 = cvt_pk_bf16(hB[0], hB[1]);
            const unsigned b23 = cvt_pk_bf16(hB[2], hB[3]);
            *reinterpret_cast<short*>(SH + hw_off[0]) = (short)(b01 & 0xFFFF);
            *reinterpret_cast<short*>(SH + hw_off[1]) = (short)(b01 >> 16);
            *reinterpret_cast<short*>(SH + hw_off[2]) = (short)(b23 & 0xFFFF);
            *reinterpret_cast<short*>(SH + hw_off[3]) = (short)(b23 >> 16);
        }

        // 5. x-part of step+1's gates (MFMA pipe; overlaps nonlin + barrier wait)
        #pragma unroll
        for (int g = 0; g < 4; ++g) {
            v4f a; a[0] = bias[g]; a[1] = bias[g]; a[2] = bias[g]; a[3] = bias[g];
            a = __builtin_amdgcn_mfma_f32_16x16x32_bf16(pxA0, Bf[0][g][0], a, 0, 0, 0);
            xaccA[g] = __builtin_amdgcn_mfma_f32_16x16x32_bf16(pxA1, Bf[0][g][1], a, 0, 0, 0);
            v4f b; b[0] = bias[g]; b[1] = bias[g]; b[2] = bias[g]; b[3] = bias[g];
            b = __builtin_amdgcn_mfma_f32_16x16x32_bf16(pxB0, Bf[0][g][0], b, 0, 0, 0);
            xaccB[g] = __builtin_amdgcn_mfma_f32_16x16x32_bf16(pxB1, Bf[0][g][1], b, 0, 0, 0);
        }

        // 6. LDS-only barrier (x + gather loads stay in flight)
        block_sync_lds();

        // 7. roll prefetch regs (unroll-2 lets the allocator rename these)
        pxA0 = nxA0; pxA1 = nxA1; pxB0 = nxB0; pxB1 = nxB1;
    }

    // ======================= FUSED POST EPILOGUE =======================
    // batches q=0,1 -> global b = blk*2 + q; local pair p = q*16 + m.

    // 1. stage agg/33 as bf16 into dead sH tiles 0,1 (same swizzle as h)
    {
        const float sc = 1.0f / 33.0f;
        uint4 pk;
        pk.x = cvt_pk_bf16(gacc[0] * sc, gacc[1] * sc);
        pk.y = cvt_pk_bf16(gacc[2] * sc, gacc[3] * sc);
        pk.z = cvt_pk_bf16(gacc[4] * sc, gacc[5] * sc);
        pk.w = cvt_pk_bf16(gacc[6] * sc, gacc[7] * sc);
        const int row = gpair & 15;
        const int off = ((gpair >> 4) << 11) + row * 128 + ((gec ^ (row & 7)) << 4);
        *reinterpret_cast<uint4*>(sHb + off) = pk;
    }
    __syncthreads();

    // 2. m_gcn = relu(agg @ gcn_W^T + b) via MFMA; fus = h + m_gcn.
    {
        short8 agA0 = *reinterpret_cast<const short8*>(sHb + offA0);
        short8 agA1 = *reinterpret_cast<const short8*>(sHb + offA1);
        short8 agB0 = *reinterpret_cast<const short8*>(sHb + 2048 + offA0);
        short8 agB1 = *reinterpret_cast<const short8*>(sHb + 2048 + offA1);
        v4f z4 = {0.0f, 0.0f, 0.0f, 0.0f};
        v4f gA = __builtin_amdgcn_mfma_f32_16x16x32_bf16(agA0, Bg[0], z4, 0, 0, 0);
        gA = __builtin_amdgcn_mfma_f32_16x16x32_bf16(agA1, Bg[1], gA, 0, 0, 0);
        v4f gB = __builtin_amdgcn_mfma_f32_16x16x32_bf16(agB0, Bg[0], z4, 0, 0, 0);
        gB = __builtin_amdgcn_mfma_f32_16x16x32_bf16(agB1, Bg[1], gB, 0, 0, 0);
        const int e = w * 16 + lr;
        #pragma unroll
        for (int r = 0; r < 4; ++r) {
            sFus[lb * 4 + r][e]      = hA[r] + fmaxf(gA[r] + gb, 0.0f);
            sFus[16 + lb * 4 + r][e] = hB[r] + fmaxf(gB[r] + gb, 0.0f);
        }
    }
    __syncthreads();

    // 3. PNA reduce over M (amp = 1 exactly)
    if (t < 128) {
        const int q = t >> 6, e = t & 63;
        float mn = 0.0f, mx = -INFINITY;
        #pragma unroll
        for (int m = 0; m < MM; ++m) { float v = sFus[q * 16 + m][e]; mn += v; mx = fmaxf(mx, v); }
        mn *= (1.0f / 16.0f);
        sF[q][e] = mn; sF[q][64 + e] = mx; sF[q][128 + e] = mn; sF[q][192 + e] = mx;
    }
    __syncthreads();

    // 4. h1 = relu(feats @ pna_W1 + b1): 256->64, k split 2x128 over 256 thr
    {
        const int q = t >> 7, kh = (t >> 6) & 1, j = t & 63;
        float p = 0.0f;
        const float* Wp = pna_W1 + (size_t)(kh * 128) * 64 + j;
        const float* fp = &sF[q][kh * 128];
        #pragma unroll 16
        for (int k = 0; k < 128; ++k) p = fmaf(fp[k], Wp[(size_t)k * 64], p);
        sP[q][kh][j] = p;
    }
    __syncthreads();
    if (t < 128) {
        const int q = t >> 6, j = t & 63;
        sH1[q][j] = fmaxf(pna_b1[j] + sP[q][0][j] + sP[q][1][j], 0.0f);
    }
    __syncthreads();

    // 5. h2 = relu(h1 @ pna_W2 + b2): k split 2x32 over 256 thr
    {
        const int q = t >> 7, kh = (t >> 6) & 1, j = t & 63;
        float p = 0.0f;
        #pragma unroll
        for (int k = 0; k < 32; ++k)
            p = fmaf(sH1[q][kh * 32 + k], pna_W2[(size_t)(kh * 32 + k) * 64 + j], p);
        sP[q][kh][j] = p;
    }
    __syncthreads();
    if (t < 128) {
        const int q = t >> 6, j = t & 63;
        sH2[q][j] = fmaxf(pna_b2[j] + sP[q][0][j] + sP[q][1][j], 0.0f);
    }
    __syncthreads();

    // 6. grp = h2 @ pna_W3 + b3: k split 2x32 over 256 thr
    {
        const int q = t >> 7, kh = (t >> 6) & 1, j = t & 63;
        float p = 0.0f;
        #pragma unroll
        for (int k = 0; k < 32; ++k)
            p = fmaf(sH2[q][kh * 32 + k], pna_W3[(size_t)(kh * 32 + k) * 64 + j], p);
        sP[q][kh][j] = p;
    }
    __syncthreads();
    if (t < 128) {
        const int q = t >> 6, j = t & 63;
        sGrp[q][j] = pna_b3[j] + sP[q][0][j] + sP[q][1][j];
    }
    __syncthreads();

    // 7. predict layer 1: 128 threads, k split 8x24; then 16-thread combine
    if (t < 128) {
        const int q = t >> 6, kg = (t >> 3) & 7, j = t & 7;
        float a = 0.0f;
        #pragma unroll
        for (int kk = 0; kk < 24; ++kk) {
            const int k = kg * 24 + kk;
            const float cv = (k < 64) ? sGrp[q][k] * sActe[q][k]
                                      : ((k < 128) ? sGrp[q][k - 64] : sActe[q][k - 128]);
            a = fmaf(cv, pred_W1[k * 8 + j], a);
        }
        sP7[q][kg][j] = a;
    }
    __syncthreads();
    if (t < 16) {
        const int q = t >> 3, j = t & 7;
        float a = pred_b1[j];
        #pragma unroll
        for (int kg = 0; kg < 8; ++kg) a += sP7[q][kg][j];
        sHH[q][j] = fmaxf(a, 0.0f);
    }
    __syncthreads();
    if (t < 2) {
        float y = pred_b2[0];
        #pragma unroll
        for (int jj = 0; jj < 8; ++jj) y = fmaf(sHH[t][jj], pred_W2[jj], y);
        out[blk * 2 + t] = 1.0f / (1.0f + expf(-y));
    }
}

extern "C" void kernel_launch(void* const* d_in, const int* in_sizes, int n_in,
                              void* d_out, int out_size, void* d_ws, size_t ws_size,
                              hipStream_t stream) {
    const int*   members    = (const int*)d_in[0];
    const int*   neighbors  = (const int*)d_in[1];
    const int*   act_inputs = (const int*)d_in[2];
    const int*   act_seqs   = (const int*)d_in[3];
    const float* act_table  = (const float*)d_in[4];
    const float* user_table = (const float*)d_in[5];
    const float* W_ih       = (const float*)d_in[6];
    const float* W_hh       = (const float*)d_in[7];
    const float* b_ih       = (const float*)d_in[8];
    const float* b_hh       = (const float*)d_in[9];
    const float* gcn_W      = (const float*)d_in[10];
    const float* gcn_b      = (const float*)d_in[11];
    const float* pna_W1     = (const float*)d_in[12];
    const float* pna_b1     = (const float*)d_in[13];
    const float* pna_W2     = (const float*)d_in[14];
    const float* pna_b2     = (const float*)d_in[15];
    const float* pna_W3     = (const float*)d_in[16];
    const float* pna_b3     = (const float*)d_in[17];
    const float* pred_W1    = (const float*)d_in[18];
    const float* pred_b1    = (const float*)d_in[19];
    const float* pred_W2    = (const float*)d_in[20];
    const float* pred_b2    = (const float*)d_in[21];

    unsigned short* act_bf = (unsigned short*)d_ws;   // 12.8 MB bf16 table

    cvt_table<<<dim3((NACT * EE / 8 + 255) / 256), dim3(256), 0, stream>>>(
        act_table, (unsigned*)act_bf);

    lstm_fused<<<dim3(512), dim3(256), 0, stream>>>(
        act_seqs, act_bf, members, neighbors, user_table,
        W_ih, W_hh, b_ih, b_hh,
        act_inputs, act_table,
        gcn_W, gcn_b, pna_W1, pna_b1, pna_W2, pna_b2, pna_W3, pna_b3,
        pred_W1, pred_b1, pred_W2, pred_b2, (float*)d_out);
}

// Round 17
// 103.374 us; speedup vs baseline: 1.7276x; 1.0171x over previous
//
#include <hip/hip_runtime.h>
#include <hip/hip_bf16.h>
#include <math.h>

// Problem constants (match reference)
#define BB   1024
#define MM   16
#define KK   32
#define LL   50
#define EE   64
#define NACT 100000

typedef __attribute__((ext_vector_type(8))) short short8;
typedef float v4f __attribute__((ext_vector_type(4)));

__device__ __forceinline__ float rcpf(float x) { return __builtin_amdgcn_rcpf(x); }
// native 2^x (v_exp_f32 IS exp2)
__device__ __forceinline__ float exp2_fast(float x) {
    float r;
    asm("v_exp_f32 %0, %1" : "=v"(r) : "v"(x));
    return r;
}

// packed f32x2 -> bf16x2 (lo->low16, hi->high16), RNE
__device__ __forceinline__ unsigned cvt_pk_bf16(float lo, float hi) {
    unsigned r;
    asm("v_cvt_pk_bf16_f32 %0, %1, %2" : "=v"(r) : "v"(lo), "v"(hi));
    return r;
}

// Block-wide barrier that does NOT drain vmcnt: LDS writes are made visible
// (lgkmcnt(0)) but global prefetch loads stay in flight across the barrier.
__device__ __forceinline__ void block_sync_lds() {
    __builtin_amdgcn_sched_barrier(0);
    asm volatile("s_waitcnt lgkmcnt(0)" ::: "memory");
    __builtin_amdgcn_s_barrier();
    __builtin_amdgcn_sched_barrier(0);
}

// ---------------------------------------------------------------------------
// Pre-pass: act_table f32 -> bf16 (row-major, same layout). 8 floats/thread.
// ---------------------------------------------------------------------------
__global__ __launch_bounds__(256)
void cvt_table(const float* __restrict__ src, unsigned* __restrict__ dst)
{
    const int i = blockIdx.x * 256 + threadIdx.x;          // unit = 8 floats
    if (i < (NACT * EE) / 8) {
        const float4* s = reinterpret_cast<const float4*>(src) + (size_t)i * 2;
        float4 a = s[0], b = s[1];
        uint4 o;
        o.x = cvt_pk_bf16(a.x, a.y);
        o.y = cvt_pk_bf16(a.z, a.w);
        o.z = cvt_pk_bf16(b.x, b.y);
        o.w = cvt_pk_bf16(b.z, b.w);
        reinterpret_cast<uint4*>(dst)[i] = o;
    }
}

// ---------------------------------------------------------------------------
// FULLY-FUSED kernel (r16 structure) + critical-path trims:
// (a) s_setprio(1) around the recurrence-critical section (h-read -> h@Whh
//     MFMA -> nonlin -> h-write); off-path work (x-GEMM for step+1, gather,
//     prefetch) runs at prio 0 so the CU scheduler prefers whichever of the
//     two co-resident blocks' waves is inside its serial chain.
// (b) cell state kept pre-scaled: c~ = 2*log2e*c; the 2L2E scale is folded
//     into tanh(g)'s output, deleting the cc*(2L2E) multiply from the
//     exp2(c) serial chain.
// Everything else (dual-chain, exp2 fold, gather fusion, x-pipeline,
// MFMA epilogue) is r16.
// ---------------------------------------------------------------------------
__global__ __launch_bounds__(256, 2)
void lstm_fused(const int* __restrict__ act_seqs, const unsigned short* __restrict__ act_bf,
                const int* __restrict__ members, const int* __restrict__ neighbors,
                const float* __restrict__ user_table,
                const float* __restrict__ W_ih, const float* __restrict__ W_hh,
                const float* __restrict__ b_ih, const float* __restrict__ b_hh,
                const int* __restrict__ act_inputs, const float* __restrict__ act_table,
                const float* __restrict__ gcn_W, const float* __restrict__ gcn_b,
                const float* __restrict__ pna_W1, const float* __restrict__ pna_b1,
                const float* __restrict__ pna_W2, const float* __restrict__ pna_b2,
                const float* __restrict__ pna_W3, const float* __restrict__ pna_b3,
                const float* __restrict__ pred_W1, const float* __restrict__ pred_b1,
                const float* __restrict__ pred_W2, const float* __restrict__ pred_b2,
                float* __restrict__ out)
{
    // --- loop-phase LDS
    __shared__ __align__(16) short sH[4][1024];   // h dbuf (bf16 swizzled), 8 KB
    __shared__ int sIdx[32 * LL];                 // 6.4 KB
    __shared__ int sNbr[32 * 33];                 // 4.2 KB
    // --- epilogue LDS
    __shared__ float sFus[32][66];                // padded: conflict-free col reads
    __shared__ float sF[2][256];                  // PNA feats
    __shared__ float sP[2][2][64];                // k-split partials
    __shared__ float sP7[2][8][8];                // predict partials
    __shared__ float sH1[2][64];
    __shared__ float sH2[2][64];
    __shared__ float sGrp[2][64];
    __shared__ float sActe[2][64];
    __shared__ float sHH[2][8];

    const int t    = threadIdx.x;
    const int blk  = blockIdx.x;
    const int lane = t & 63;
    const int w    = t >> 6;        // wave id = e-block (0..3)
    const int lr   = lane & 15;     // A row (seq) / B,D col selector
    const int lb   = lane >> 4;     // k-block / D row-block selector

    // --- this block's indices (contiguous 1600 ints, coalesced)
    for (int i = t; i < 32 * LL; i += 256) sIdx[i] = act_seqs[blk * (32 * LL) + i];
    // --- gather row ids: pair p (= global b*16+m = blk*32+p), j=0 member, 1..32 nbrs
    for (int i = t; i < 32 * 33; i += 256) {
        const int p = i / 33, j = i - p * 33;
        const int base = blk * 32 + p;
        sNbr[i] = (j == 0) ? members[base] : neighbors[base * KK + j - 1];
    }
    // --- stage act_e for both batches (prologue: latency hidden under setup)
    if (t < 128) {
        const int q = t >> 6, e = t & 63;
        sActe[q][e] = act_table[(size_t)act_inputs[blk * 2 + q] * EE + e];
    }

    // per-gate exp2 fold scales (i,f,o: -log2e; g: +2*log2e)
    const float L2E = 1.44269504088896f;
    float gscale[4];
    gscale[0] = -L2E; gscale[1] = -L2E; gscale[2] = 2.0f * L2E; gscale[3] = -L2E;

    // --- weights -> register B-frags, SCALED. gates = in @ W^T => B[k][j]=W[j][k].
    short8 Bf[2][4][2];   // [mat(ih,hh)][gate][ks]
    #pragma unroll
    for (int mat = 0; mat < 2; ++mat) {
        const float* W = mat ? W_hh : W_ih;
        #pragma unroll
        for (int g = 0; g < 4; ++g) {
            const int j = g * 64 + w * 16 + lr;
            const float sc = gscale[g];
            #pragma unroll
            for (int ks = 0; ks < 2; ++ks) {
                const float4* p = reinterpret_cast<const float4*>(&W[(size_t)j * 64 + ks * 32 + lb * 8]);
                float4 v0 = p[0], v1 = p[1];
                uint4 o;
                o.x = cvt_pk_bf16(sc * v0.x, sc * v0.y);
                o.y = cvt_pk_bf16(sc * v0.z, sc * v0.w);
                o.z = cvt_pk_bf16(sc * v1.x, sc * v1.y);
                o.w = cvt_pk_bf16(sc * v1.z, sc * v1.w);
                Bf[mat][g][ks] = __builtin_bit_cast(short8, o);
            }
        }
    }
    // --- gcn_W -> register B-frags (epilogue MFMA), unscaled bf16 RNE
    short8 Bg[2];
    #pragma unroll
    for (int ks = 0; ks < 2; ++ks) {
        const int j = w * 16 + lr;
        const float4* p = reinterpret_cast<const float4*>(&gcn_W[(size_t)j * 64 + ks * 32 + lb * 8]);
        float4 v0 = p[0], v1 = p[1];
        uint4 o;
        o.x = cvt_pk_bf16(v0.x, v0.y);
        o.y = cvt_pk_bf16(v0.z, v0.w);
        o.z = cvt_pk_bf16(v1.x, v1.y);
        o.w = cvt_pk_bf16(v1.z, v1.w);
        Bg[ks] = __builtin_bit_cast(short8, o);
    }
    const float gb = gcn_b[w * 16 + lr];

    float bias[4];
    #pragma unroll
    for (int g = 0; g < 4; ++g) {
        const int j = g * 64 + w * 16 + lr;
        bias[g] = gscale[g] * (b_ih[j] + b_hh[j]);
    }

    // cell state kept pre-scaled: c~ = 2*L2E*c (so exp2 arg is c~ directly)
    float hA[4], cA[4], hB[4], cB[4];
    #pragma unroll
    for (int r = 0; r < 4; ++r) { hA[r] = 0.0f; cA[r] = 0.0f; hB[r] = 0.0f; cB[r] = 0.0f; }

    // zero buf0 (tiles 0,1 = 4096 B = 256 x uint4)
    reinterpret_cast<uint4*>(sH)[t] = make_uint4(0u, 0u, 0u, 0u);
    __syncthreads();   // sIdx + sNbr + sActe + sH buf0 visible (once)

    // --- gather lane mapping: pair p = t>>3 owns row blk*32+p; chunk ec = t&7
    const int gpair = t >> 3;
    const int gec   = t & 7;
    const float* gut = user_table + (size_t)gec * 8;
    float gacc[8];
    #pragma unroll
    for (int q = 0; q < 8; ++q) gacc[q] = 0.0f;
    // pre-issue gather row 0 (BEFORE x pre-loads: older in vmcnt FIFO)
    float4 gld0, gld1;
    {
        const int gi = sNbr[gpair * 33 + 0];
        const float4* gp = reinterpret_cast<const float4*>(gut + (size_t)gi * EE);
        gld0 = gp[0]; gld1 = gp[1];
    }

    // --- x gather: lane's frag = bytes [id*128 + lb*16] and +64.
    const char* tbl8 = reinterpret_cast<const char*>(act_bf) + lb * 16;
    const int ibA = lr * LL;           // chain A: seq lr
    const int ibB = (16 + lr) * LL;    // chain B: seq 16+lr

    // prologue: load x_0, compute xacc for step 0; load x_1 -> px; idx -> x_2
    int idA = sIdx[ibA + 0], idB = sIdx[ibB + 0];
    short8 c0A0 = *reinterpret_cast<const short8*>(tbl8 + (size_t)idA * 128);
    short8 c0A1 = *reinterpret_cast<const short8*>(tbl8 + (size_t)idA * 128 + 64);
    short8 c0B0 = *reinterpret_cast<const short8*>(tbl8 + (size_t)idB * 128);
    short8 c0B1 = *reinterpret_cast<const short8*>(tbl8 + (size_t)idB * 128 + 64);
    idA = sIdx[ibA + 1]; idB = sIdx[ibB + 1];
    short8 pxA0 = *reinterpret_cast<const short8*>(tbl8 + (size_t)idA * 128);
    short8 pxA1 = *reinterpret_cast<const short8*>(tbl8 + (size_t)idA * 128 + 64);
    short8 pxB0 = *reinterpret_cast<const short8*>(tbl8 + (size_t)idB * 128);
    short8 pxB1 = *reinterpret_cast<const short8*>(tbl8 + (size_t)idB * 128 + 64);
    idA = sIdx[ibA + 2]; idB = sIdx[ibB + 2];

    v4f xaccA[4], xaccB[4];
    #pragma unroll
    for (int g = 0; g < 4; ++g) {
        v4f a; a[0] = bias[g]; a[1] = bias[g]; a[2] = bias[g]; a[3] = bias[g];
        a = __builtin_amdgcn_mfma_f32_16x16x32_bf16(c0A0, Bf[0][g][0], a, 0, 0, 0);
        xaccA[g] = __builtin_amdgcn_mfma_f32_16x16x32_bf16(c0A1, Bf[0][g][1], a, 0, 0, 0);
        v4f b; b[0] = bias[g]; b[1] = bias[g]; b[2] = bias[g]; b[3] = bias[g];
        b = __builtin_amdgcn_mfma_f32_16x16x32_bf16(c0B0, Bf[0][g][0], b, 0, 0, 0);
        xaccB[g] = __builtin_amdgcn_mfma_f32_16x16x32_bf16(c0B1, Bf[0][g][1], b, 0, 0, 0);
    }

    // LDS byte offsets (loop-invariant)
    const int offA0 = lr * 128 + ((lb ^ (lr & 7)) << 4);
    const int offA1 = lr * 128 + (((lb + 4) ^ (lr & 7)) << 4);
    int hw_off[4];
    #pragma unroll
    for (int r = 0; r < 4; ++r) {
        const int s = lb * 4 + r, e = w * 16 + lr;
        hw_off[r] = s * 128 + ((((e >> 3) ^ (s & 7)) << 4)) + (e & 7) * 2;
    }
    char* const sHb = reinterpret_cast<char*>(sH);

    const float TL2 = 2.0f * L2E;   // 2*log2e

    #pragma unroll 2
    for (int step = 0; step < LL; ++step) {
        const int cb  = (step & 1) << 12;   // current buf base: 0 or 4096
        const int nb_ = cb ^ 4096;          // next buf base

        // 0. fused GCN gather (low prio): accumulate row `step`, issue row step+1
        if (step < 33) {
            gacc[0] += gld0.x; gacc[1] += gld0.y; gacc[2] += gld0.z; gacc[3] += gld0.w;
            gacc[4] += gld1.x; gacc[5] += gld1.y; gacc[6] += gld1.z; gacc[7] += gld1.w;
            if (step < 32) {
                const int gi = sNbr[gpair * 33 + step + 1];
                const float4* gp = reinterpret_cast<const float4*>(gut + (size_t)gi * EE);
                gld0 = gp[0]; gld1 = gp[1];
            }
        }

        // 1. issue x prefetch for step+2 (stays in flight across the barrier)
        short8 nxA0 = *reinterpret_cast<const short8*>(tbl8 + (size_t)idA * 128);
        short8 nxA1 = *reinterpret_cast<const short8*>(tbl8 + (size_t)idA * 128 + 64);
        short8 nxB0 = *reinterpret_cast<const short8*>(tbl8 + (size_t)idB * 128);
        short8 nxB1 = *reinterpret_cast<const short8*>(tbl8 + (size_t)idB * 128 + 64);
        {
            const int s2 = (step + 3 < LL) ? (step + 3) : (LL - 1);
            idA = sIdx[ibA + s2]; idB = sIdx[ibB + s2];
        }

        // ---- recurrence-critical section: prefer this wave on the CU ----
        __builtin_amdgcn_s_setprio(1);

        // 2. read h A-frags for both chains (swizzled, conflict-free)
        short8 ahA0 = *reinterpret_cast<const short8*>(sHb + cb + offA0);
        short8 ahA1 = *reinterpret_cast<const short8*>(sHb + cb + offA1);
        short8 ahB0 = *reinterpret_cast<const short8*>(sHb + cb + 2048 + offA0);
        short8 ahB1 = *reinterpret_cast<const short8*>(sHb + cb + 2048 + offA1);

        // 3. acc = xacc (bias + x-part, computed last step) + h @ sWhh^T
        v4f accA[4], accB[4];
        #pragma unroll
        for (int g = 0; g < 4; ++g) {
            v4f a = __builtin_amdgcn_mfma_f32_16x16x32_bf16(ahA0, Bf[1][g][0], xaccA[g], 0, 0, 0);
            accA[g] = __builtin_amdgcn_mfma_f32_16x16x32_bf16(ahA1, Bf[1][g][1], a, 0, 0, 0);
            v4f b = __builtin_amdgcn_mfma_f32_16x16x32_bf16(ahB0, Bf[1][g][0], xaccB[g], 0, 0, 0);
            accB[g] = __builtin_amdgcn_mfma_f32_16x16x32_bf16(ahB1, Bf[1][g][1], b, 0, 0, 0);
        }

        // 4. gate nonlinearities + h writes. c kept pre-scaled (c~ = 2L2E*c):
        //    tgs = 2L2E*tanh(g) = fmaf(-2*TL2, rcp, TL2); exp2 arg is c~ directly.
        {
            char* SH = sHb + nb_;
            #pragma unroll
            for (int r = 0; r < 4; ++r) {
                const float si = rcpf(1.0f + exp2_fast(accA[0][r]));
                const float sf = rcpf(1.0f + exp2_fast(accA[1][r]));
                const float tgs = fmaf(-2.0f * TL2, rcpf(1.0f + exp2_fast(accA[2][r])), TL2);
                const float so = rcpf(1.0f + exp2_fast(accA[3][r]));
                const float cc = fmaf(sf, cA[r], si * tgs);   // pre-scaled cell
                cA[r] = cc;
                hA[r] = so * fmaf(-2.0f, rcpf(1.0f + exp2_fast(cc)), 1.0f);
            }
            const unsigned a01 = cvt_pk_bf16(hA[0], hA[1]);
            const unsigned a23 = cvt_pk_bf16(hA[2], hA[3]);
            *reinterpret_cast<short*>(SH + hw_off[0]) = (short)(a01 & 0xFFFF);
            *reinterpret_cast<short*>(SH + hw_off[1]) = (short)(a01 >> 16);
            *reinterpret_cast<short*>(SH + hw_off[2]) = (short)(a23 & 0xFFFF);
            *reinterpret_cast<short*>(SH + hw_off[3]) = (short)(a23 >> 16);
            SH += 2048;
            #pragma unroll
            for (int r = 0; r < 4; ++r) {
                const float si = rcpf(1.0f + exp2_fast(accB[0][r]));
                const float sf = rcpf(1.0f + exp2_fast(accB[1][r]));
                const float tgs = fmaf(-2.0f * TL2, rcpf(1.0f + exp2_fast(accB[2][r])), TL2);
                const float so = rcpf(1.0f + exp2_fast(accB[3][r]));
                const float cc = fmaf(sf, cB[r], si * tgs);
                cB[r] = cc;
                hB[r] = so * fmaf(-2.0f, rcpf(1.0f + exp2_fast(cc)), 1.0f);
            }
            const unsigned b01 = cvt_pk_bf16(hB[0], hB[1]);
            const unsigned b23 = cvt_pk_bf16(hB[2], hB[3]);
            *reinterpret_cast<short*>(SH + hw_off[0]) = (short)(b01 & 0xFFFF);
            *reinterpret_cast<short*>(SH + hw_off[1]) = (short)(b01 >> 16);
            *reinterpret_cast<short*>(SH + hw_off[2]) = (short)(b23 & 0xFFFF);
            *reinterpret_cast<short*>(SH + hw_off[3]) = (short)(b23 >> 16);
        }

        __builtin_amdgcn_s_setprio(0);
        // ---- end critical section ----

        // 5. x-part of step+1's gates (off critical path; overlaps barrier wait)
        #pragma unroll
        for (int g = 0; g < 4; ++g) {
            v4f a; a[0] = bias[g]; a[1] = bias[g]; a[2] = bias[g]; a[3] = bias[g];
            a = __builtin_amdgcn_mfma_f32_16x16x32_bf16(pxA0, Bf[0][g][0], a, 0, 0, 0);
            xaccA[g] = __builtin_amdgcn_mfma_f32_16x16x32_bf16(pxA1, Bf[0][g][1], a, 0, 0, 0);
            v4f b; b[0] = bias[g]; b[1] = bias[g]; b[2] = bias[g]; b[3] = bias[g];
            b = __builtin_amdgcn_mfma_f32_16x16x32_bf16(pxB0, Bf[0][g][0], b, 0, 0, 0);
            xaccB[g] = __builtin_amdgcn_mfma_f32_16x16x32_bf16(pxB1, Bf[0][g][1], b, 0, 0, 0);
        }

        // 6. LDS-only barrier (x + gather loads stay in flight)
        block_sync_lds();

        // 7. roll prefetch regs (unroll-2 lets the allocator rename these)
        pxA0 = nxA0; pxA1 = nxA1; pxB0 = nxB0; pxB1 = nxB1;
    }

    // ======================= FUSED POST EPILOGUE =======================
    // batches q=0,1 -> global b = blk*2 + q; local pair p = q*16 + m.

    // 1. stage agg/33 as bf16 into dead sH tiles 0,1 (same swizzle as h)
    {
        const float sc = 1.0f / 33.0f;
        uint4 pk;
        pk.x = cvt_pk_bf16(gacc[0] * sc, gacc[1] * sc);
        pk.y = cvt_pk_bf16(gacc[2] * sc, gacc[3] * sc);
        pk.z = cvt_pk_bf16(gacc[4] * sc, gacc[5] * sc);
        pk.w = cvt_pk_bf16(gacc[6] * sc, gacc[7] * sc);
        const int row = gpair & 15;
        const int off = ((gpair >> 4) << 11) + row * 128 + ((gec ^ (row & 7)) << 4);
        *reinterpret_cast<uint4*>(sHb + off) = pk;
    }
    __syncthreads();

    // 2. m_gcn = relu(agg @ gcn_W^T + b) via MFMA; fus = h + m_gcn.
    {
        short8 agA0 = *reinterpret_cast<const short8*>(sHb + offA0);
        short8 agA1 = *reinterpret_cast<const short8*>(sHb + offA1);
        short8 agB0 = *reinterpret_cast<const short8*>(sHb + 2048 + offA0);
        short8 agB1 = *reinterpret_cast<const short8*>(sHb + 2048 + offA1);
        v4f z4 = {0.0f, 0.0f, 0.0f, 0.0f};
        v4f gA = __builtin_amdgcn_mfma_f32_16x16x32_bf16(agA0, Bg[0], z4, 0, 0, 0);
        gA = __builtin_amdgcn_mfma_f32_16x16x32_bf16(agA1, Bg[1], gA, 0, 0, 0);
        v4f gB = __builtin_amdgcn_mfma_f32_16x16x32_bf16(agB0, Bg[0], z4, 0, 0, 0);
        gB = __builtin_amdgcn_mfma_f32_16x16x32_bf16(agB1, Bg[1], gB, 0, 0, 0);
        const int e = w * 16 + lr;
        #pragma unroll
        for (int r = 0; r < 4; ++r) {
            sFus[lb * 4 + r][e]      = hA[r] + fmaxf(gA[r] + gb, 0.0f);
            sFus[16 + lb * 4 + r][e] = hB[r] + fmaxf(gB[r] + gb, 0.0f);
        }
    }
    __syncthreads();

    // 3. PNA reduce over M (amp = 1 exactly)
    if (t < 128) {
        const int q = t >> 6, e = t & 63;
        float mn = 0.0f, mx = -INFINITY;
        #pragma unroll
        for (int m = 0; m < MM; ++m) { float v = sFus[q * 16 + m][e]; mn += v; mx = fmaxf(mx, v); }
        mn *= (1.0f / 16.0f);
        sF[q][e] = mn; sF[q][64 + e] = mx; sF[q][128 + e] = mn; sF[q][192 + e] = mx;
    }
    __syncthreads();

    // 4. h1 = relu(feats @ pna_W1 + b1): 256->64, k split 2x128 over 256 thr
    {
        const int q = t >> 7, kh = (t >> 6) & 1, j = t & 63;
        float p = 0.0f;
        const float* Wp = pna_W1 + (size_t)(kh * 128) * 64 + j;
        const float* fp = &sF[q][kh * 128];
        #pragma unroll 16
        for (int k = 0; k < 128; ++k) p = fmaf(fp[k], Wp[(size_t)k * 64], p);
        sP[q][kh][j] = p;
    }
    __syncthreads();
    if (t < 128) {
        const int q = t >> 6, j = t & 63;
        sH1[q][j] = fmaxf(pna_b1[j] + sP[q][0][j] + sP[q][1][j], 0.0f);
    }
    __syncthreads();

    // 5. h2 = relu(h1 @ pna_W2 + b2): k split 2x32 over 256 thr
    {
        const int q = t >> 7, kh = (t >> 6) & 1, j = t & 63;
        float p = 0.0f;
        #pragma unroll
        for (int k = 0; k < 32; ++k)
            p = fmaf(sH1[q][kh * 32 + k], pna_W2[(size_t)(kh * 32 + k) * 64 + j], p);
        sP[q][kh][j] = p;
    }
    __syncthreads();
    if (t < 128) {
        const int q = t >> 6, j = t & 63;
        sH2[q][j] = fmaxf(pna_b2[j] + sP[q][0][j] + sP[q][1][j], 0.0f);
    }
    __syncthreads();

    // 6. grp = h2 @ pna_W3 + b3: k split 2x32 over 256 thr
    {
        const int q = t >> 7, kh = (t >> 6) & 1, j = t & 63;
        float p = 0.0f;
        #pragma unroll
        for (int k = 0; k < 32; ++k)
            p = fmaf(sH2[q][kh * 32 + k], pna_W3[(size_t)(kh * 32 + k) * 64 + j], p);
        sP[q][kh][j] = p;
    }
    __syncthreads();
    if (t < 128) {
        const int q = t >> 6, j = t & 63;
        sGrp[q][j] = pna_b3[j] + sP[q][0][j] + sP[q][1][j];
    }
    __syncthreads();

    // 7. predict layer 1: 128 threads, k split 8x24; then 16-thread combine
    if (t < 128) {
        const int q = t >> 6, kg = (t >> 3) & 7, j = t & 7;
        float a = 0.0f;
        #pragma unroll
        for (int kk = 0; kk < 24; ++kk) {
            const int k = kg * 24 + kk;
            const float cv = (k < 64) ? sGrp[q][k] * sActe[q][k]
                                      : ((k < 128) ? sGrp[q][k - 64] : sActe[q][k - 128]);
            a = fmaf(cv, pred_W1[k * 8 + j], a);
        }
        sP7[q][kg][j] = a;
    }
    __syncthreads();
    if (t < 16) {
        const int q = t >> 3, j = t & 7;
        float a = pred_b1[j];
        #pragma unroll
        for (int kg = 0; kg < 8; ++kg) a += sP7[q][kg][j];
        sHH[q][j] = fmaxf(a, 0.0f);
    }
    __syncthreads();
    if (t < 2) {
        float y = pred_b2[0];
        #pragma unroll
        for (int jj = 0; jj < 8; ++jj) y = fmaf(sHH[t][jj], pred_W2[jj], y);
        out[blk * 2 + t] = 1.0f / (1.0f + expf(-y));
    }
}

extern "C" void kernel_launch(void* const* d_in, const int* in_sizes, int n_in,
                              void* d_out, int out_size, void* d_ws, size_t ws_size,
                              hipStream_t stream) {
    const int*   members    = (const int*)d_in[0];
    const int*   neighbors  = (const int*)d_in[1];
    const int*   act_inputs = (const int*)d_in[2];
    const int*   act_seqs   = (const int*)d_in[3];
    const float* act_table  = (const float*)d_in[4];
    const float* user_table = (const float*)d_in[5];
    const float* W_ih       = (const float*)d_in[6];
    const float* W_hh       = (const float*)d_in[7];
    const float* b_ih       = (const float*)d_in[8];
    const float* b_hh       = (const float*)d_in[9];
    const float* gcn_W      = (const float*)d_in[10];
    const float* gcn_b      = (const float*)d_in[11];
    const float* pna_W1     = (const float*)d_in[12];
    const float* pna_b1     = (const float*)d_in[13];
    const float* pna_W2     = (const float*)d_in[14];
    const float* pna_b2     = (const float*)d_in[15];
    const float* pna_W3     = (const float*)d_in[16];
    const float* pna_b3     = (const float*)d_in[17];
    const float* pred_W1    = (const float*)d_in[18];
    const float* pred_b1    = (const float*)d_in[19];
    const float* pred_W2    = (const float*)d_in[20];
    const float* pred_b2    = (const float*)d_in[21];

    unsigned short* act_bf = (unsigned short*)d_ws;   // 12.8 MB bf16 table

    cvt_table<<<dim3((NACT * EE / 8 + 255) / 256), dim3(256), 0, stream>>>(
        act_table, (unsigned*)act_bf);

    lstm_fused<<<dim3(512), dim3(256), 0, stream>>>(
        act_seqs, act_bf, members, neighbors, user_table,
        W_ih, W_hh, b_ih, b_hh,
        act_inputs, act_table,
        gcn_W, gcn_b, pna_W1, pna_b1, pna_W2, pna_b2, pna_W3, pna_b3,
        pred_W1, pred_b1, pred_W2, pred_b2, (float*)d_out);
}